// Round 1
// baseline (2776.843 us; speedup 1.0000x reference)
//
#include <hip/hip_runtime.h>
#include <cmath>

#define BB 2
#define NN 2048
#define EE 1024
#define HQH 16
#define HKVH 4
#define GG 4
#define DD 64
#define KVE 256

// ---------------------------------------------------------------------------
// Tiled fp32 GEMM: C[M x OC] = A[M x K] @ W[K x OC], all row-major.
// 128x128 tile, K-step 16, 256 threads, 8x8 micro-tile per thread.
// ---------------------------------------------------------------------------
__global__ __launch_bounds__(256)
void gemm128(const float* __restrict__ A, const float* __restrict__ W,
             float* __restrict__ C, int M, int K, int OC) {
    __shared__ float As[16][132];   // transposed: As[k][m]
    __shared__ float Bs[16][132];
    int t = threadIdx.x;
    int tx = t & 15, ty = t >> 4;
    int n0 = blockIdx.x * 128;
    int m0 = blockIdx.y * 128;
    float acc[8][8];
#pragma unroll
    for (int i = 0; i < 8; ++i)
#pragma unroll
        for (int j = 0; j < 8; ++j) acc[i][j] = 0.f;

    for (int k0 = 0; k0 < K; k0 += 16) {
        // A tile: 128 rows x 16 k, store transposed
#pragma unroll
        for (int it = 0; it < 2; ++it) {
            int lin = t + it * 256;
            int r = lin >> 2;      // 0..127
            int kq = lin & 3;      // 0..3 (float4 along k)
            float4 a4 = *(const float4*)&A[(size_t)(m0 + r) * K + k0 + kq * 4];
            As[kq * 4 + 0][r] = a4.x;
            As[kq * 4 + 1][r] = a4.y;
            As[kq * 4 + 2][r] = a4.z;
            As[kq * 4 + 3][r] = a4.w;
        }
        // B tile: 16 k x 128 cols
#pragma unroll
        for (int it = 0; it < 2; ++it) {
            int lin = t + it * 256;
            int r = lin >> 5;      // 0..15
            int c4 = lin & 31;     // 0..31
            float4 b4 = *(const float4*)&W[(size_t)(k0 + r) * OC + n0 + c4 * 4];
            *(float4*)&Bs[r][c4 * 4] = b4;
        }
        __syncthreads();
#pragma unroll
        for (int kk = 0; kk < 16; ++kk) {
            float a[8], br[8];
            *(float4*)&a[0] = *(const float4*)&As[kk][ty * 8];
            *(float4*)&a[4] = *(const float4*)&As[kk][ty * 8 + 4];
            *(float4*)&br[0] = *(const float4*)&Bs[kk][tx * 8];
            *(float4*)&br[4] = *(const float4*)&Bs[kk][tx * 8 + 4];
#pragma unroll
            for (int i = 0; i < 8; ++i)
#pragma unroll
                for (int j = 0; j < 8; ++j)
                    acc[i][j] = fmaf(a[i], br[j], acc[i][j]);
        }
        __syncthreads();
    }
#pragma unroll
    for (int i = 0; i < 8; ++i) {
        float4 o0 = {acc[i][0], acc[i][1], acc[i][2], acc[i][3]};
        float4 o1 = {acc[i][4], acc[i][5], acc[i][6], acc[i][7]};
        size_t base = (size_t)(m0 + ty * 8 + i) * OC + n0 + tx * 8;
        *(float4*)&C[base] = o0;
        *(float4*)&C[base + 4] = o1;
    }
}

// ---------------------------------------------------------------------------
// Attention pass 1: per-row running max m and denom l (causal).
// One block = 256 query rows of one (b, hq). Q layout [b][n][hq*D+d],
// K layout [b][s][hkv*D+d].
// ---------------------------------------------------------------------------
__global__ __launch_bounds__(256)
void attn_ml(const float* __restrict__ Q, const float* __restrict__ K,
             float* __restrict__ mbuf, float* __restrict__ lbuf) {
    __shared__ float Ks[128][DD];   // 32 KB
    int blk = blockIdx.x;
    int ntile = blk & 7;            // N/256 = 8
    int bh = blk >> 3;
    int hq = bh & 15;
    int b = bh >> 4;
    int ih = hq >> 2;               // k head = hq / G
    int n = ntile * 256 + threadIdx.x;

    float q[DD];
    const float* qp = Q + ((size_t)(b * NN + n)) * EE + hq * DD;
#pragma unroll
    for (int d = 0; d < DD; d += 4) *(float4*)&q[d] = *(const float4*)&qp[d];

    float m = -1e30f, l = 0.f;
    int send = (ntile + 1) * 256;
    for (int s0 = 0; s0 < send; s0 += 128) {
#pragma unroll
        for (int it = 0; it < 8; ++it) {
            int lin = threadIdx.x + it * 256;
            int r = lin >> 4, c4 = lin & 15;
            *(float4*)&Ks[r][c4 * 4] =
                *(const float4*)&K[((size_t)(b * NN + s0 + r)) * KVE + ih * DD + c4 * 4];
        }
        __syncthreads();
        int smax = min(128, n - s0 + 1);
        for (int ss = 0; ss < smax; ++ss) {
            float a0 = 0.f, a1 = 0.f, a2 = 0.f, a3 = 0.f;
#pragma unroll
            for (int d = 0; d < DD; d += 4) {
                a0 = fmaf(q[d + 0], Ks[ss][d + 0], a0);
                a1 = fmaf(q[d + 1], Ks[ss][d + 1], a1);
                a2 = fmaf(q[d + 2], Ks[ss][d + 2], a2);
                a3 = fmaf(q[d + 3], Ks[ss][d + 3], a3);
            }
            float sc = ((a0 + a1) + (a2 + a3)) * 0.125f;
            float mn = fmaxf(m, sc);
            l = l * __expf(m - mn) + __expf(sc - mn);
            m = mn;
        }
        __syncthreads();
    }
    mbuf[(size_t)bh * NN + n] = m;
    lbuf[(size_t)bh * NN + n] = l;
}

// ---------------------------------------------------------------------------
// Attention pass 2: out_n = sum_s p_ns * v_s  (v head = j = hq % G).
// Writes pre-LN attention output at merged head hm = j*HKV + i.
// ---------------------------------------------------------------------------
__global__ __launch_bounds__(256)
void attn_pv(const float* __restrict__ Q, const float* __restrict__ K,
             const float* __restrict__ V, const float* __restrict__ mbuf,
             const float* __restrict__ lbuf, float* __restrict__ AO) {
    __shared__ float Ks[64][DD];    // 16 KB
    __shared__ float Vs[64][DD];    // 16 KB
    int blk = blockIdx.x;
    int ntile = blk & 7;
    int bh = blk >> 3;
    int hq = bh & 15;
    int b = bh >> 4;
    int ih = hq >> 2, jh = hq & 3;
    int hm = jh * 4 + ih;
    int n = ntile * 256 + threadIdx.x;

    float q[DD], o[DD];
    const float* qp = Q + ((size_t)(b * NN + n)) * EE + hq * DD;
#pragma unroll
    for (int d = 0; d < DD; d += 4) *(float4*)&q[d] = *(const float4*)&qp[d];
#pragma unroll
    for (int d = 0; d < DD; ++d) o[d] = 0.f;

    float m = mbuf[(size_t)bh * NN + n];
    float linv = 1.f / lbuf[(size_t)bh * NN + n];
    int send = (ntile + 1) * 256;
    for (int s0 = 0; s0 < send; s0 += 64) {
#pragma unroll
        for (int it = 0; it < 4; ++it) {
            int lin = threadIdx.x + it * 256;
            int r = lin >> 4, c4 = lin & 15;
            *(float4*)&Ks[r][c4 * 4] =
                *(const float4*)&K[((size_t)(b * NN + s0 + r)) * KVE + ih * DD + c4 * 4];
            *(float4*)&Vs[r][c4 * 4] =
                *(const float4*)&V[((size_t)(b * NN + s0 + r)) * KVE + jh * DD + c4 * 4];
        }
        __syncthreads();
        int smax = min(64, n - s0 + 1);
        for (int ss = 0; ss < smax; ++ss) {
            float a0 = 0.f, a1 = 0.f, a2 = 0.f, a3 = 0.f;
#pragma unroll
            for (int d = 0; d < DD; d += 4) {
                a0 = fmaf(q[d + 0], Ks[ss][d + 0], a0);
                a1 = fmaf(q[d + 1], Ks[ss][d + 1], a1);
                a2 = fmaf(q[d + 2], Ks[ss][d + 2], a2);
                a3 = fmaf(q[d + 3], Ks[ss][d + 3], a3);
            }
            float p = __expf(((a0 + a1) + (a2 + a3)) * 0.125f - m) * linv;
#pragma unroll
            for (int d = 0; d < DD; ++d) o[d] = fmaf(p, Vs[ss][d], o[d]);
        }
        __syncthreads();
    }
    float* op = AO + ((size_t)(b * NN + n)) * EE + hm * DD;
#pragma unroll
    for (int d = 0; d < DD; d += 4) {
        float4 v4 = {o[d], o[d + 1], o[d + 2], o[d + 3]};
        *(float4*)&op[d] = v4;
    }
}

// ---------------------------------------------------------------------------
// Attention pass 3: column sums of probs -> attn_w[b][s][hm] (mean over n).
// Block owns an s-tile; loops over n-tiles (n >= s). No atomics.
// ---------------------------------------------------------------------------
__global__ __launch_bounds__(256)
void attn_colsum(const float* __restrict__ Q, const float* __restrict__ K,
                 const float* __restrict__ mbuf, const float* __restrict__ lbuf,
                 float* __restrict__ AW) {
    __shared__ float Qs[64][DD];    // 16 KB
    __shared__ float ms[64], lsv[64];
    int blk = blockIdx.x;
    int stile = blk & 7;
    int bh = blk >> 3;
    int hq = bh & 15;
    int b = bh >> 4;
    int ih = hq >> 2, jh = hq & 3;
    int hm = jh * 4 + ih;
    int s = stile * 256 + threadIdx.x;

    float k[DD];
    const float* kp = K + ((size_t)(b * NN + s)) * KVE + ih * DD;
#pragma unroll
    for (int d = 0; d < DD; d += 4) *(float4*)&k[d] = *(const float4*)&kp[d];

    float acc = 0.f;
    for (int n0 = stile * 256; n0 < NN; n0 += 64) {
#pragma unroll
        for (int it = 0; it < 4; ++it) {
            int lin = threadIdx.x + it * 256;
            int r = lin >> 4, c4 = lin & 15;
            *(float4*)&Qs[r][c4 * 4] =
                *(const float4*)&Q[((size_t)(b * NN + n0 + r)) * EE + hq * DD + c4 * 4];
        }
        if (threadIdx.x < 64) {
            ms[threadIdx.x] = mbuf[(size_t)bh * NN + n0 + threadIdx.x];
            lsv[threadIdx.x] = 1.f / lbuf[(size_t)bh * NN + n0 + threadIdx.x];
        }
        __syncthreads();
        int lo = max(0, s - n0);
        for (int nn = lo; nn < 64; ++nn) {
            float a0 = 0.f, a1 = 0.f, a2 = 0.f, a3 = 0.f;
#pragma unroll
            for (int d = 0; d < DD; d += 4) {
                a0 = fmaf(k[d + 0], Qs[nn][d + 0], a0);
                a1 = fmaf(k[d + 1], Qs[nn][d + 1], a1);
                a2 = fmaf(k[d + 2], Qs[nn][d + 2], a2);
                a3 = fmaf(k[d + 3], Qs[nn][d + 3], a3);
            }
            acc += __expf(((a0 + a1) + (a2 + a3)) * 0.125f - ms[nn]) * lsv[nn];
        }
        __syncthreads();
    }
    AW[((size_t)b * NN + s) * HQH + hm] = acc * (1.0f / NN);
}

// ---------------------------------------------------------------------------
// LayerNorm (in place) over last dim E=1024; one block per row.
// ---------------------------------------------------------------------------
__global__ __launch_bounds__(256)
void layernorm_inplace(float* __restrict__ X, const float* __restrict__ g,
                       const float* __restrict__ bt) {
    __shared__ float red[256];
    int row = blockIdx.x;
    int t = threadIdx.x;
    float* xp = X + (size_t)row * EE;
    float4 v = *(float4*)&xp[t * 4];
    red[t] = v.x + v.y + v.z + v.w;
    __syncthreads();
    for (int off = 128; off > 0; off >>= 1) {
        if (t < off) red[t] += red[t + off];
        __syncthreads();
    }
    float mu = red[0] * (1.f / EE);
    __syncthreads();
    float dx = v.x - mu, dy = v.y - mu, dz = v.z - mu, dw = v.w - mu;
    red[t] = dx * dx + dy * dy + dz * dz + dw * dw;
    __syncthreads();
    for (int off = 128; off > 0; off >>= 1) {
        if (t < off) red[t] += red[t + off];
        __syncthreads();
    }
    float rstd = rsqrtf(red[0] * (1.f / EE) + 1e-5f);
    float4 gg = *(const float4*)&g[t * 4];
    float4 bb = *(const float4*)&bt[t * 4];
    float4 o;
    o.x = dx * rstd * gg.x + bb.x;
    o.y = dy * rstd * gg.y + bb.y;
    o.z = dz * rstd * gg.z + bb.z;
    o.w = dw * rstd * gg.w + bb.w;
    *(float4*)&xp[t * 4] = o;
}

// ---------------------------------------------------------------------------
extern "C" void kernel_launch(void* const* d_in, const int* in_sizes, int n_in,
                              void* d_out, int out_size, void* d_ws, size_t ws_size,
                              hipStream_t stream) {
    const float* x    = (const float*)d_in[0];
    const float* Wq   = (const float*)d_in[1];
    const float* Wk   = (const float*)d_in[2];
    const float* Wv   = (const float*)d_in[3];
    const float* Wout = (const float*)d_in[4];
    const float* lng  = (const float*)d_in[5];
    const float* lnb  = (const float*)d_in[6];

    float* out = (float*)d_out;                      // [B][N][E]
    float* aw  = out + (size_t)BB * NN * EE;         // [B][N][HQ]

    float* ws = (float*)d_ws;
    float* Qb = ws;                                  // B*N*E      = 4194304
    float* Kb = Qb + (size_t)BB * NN * EE;           // B*N*KV_E   = 1048576
    float* Vb = Kb + (size_t)BB * NN * KVE;          // B*N*KV_E   = 1048576
    float* mb = Vb + (size_t)BB * NN * KVE;          // B*HQ*N     = 65536
    float* lb = mb + (size_t)BB * HQH * NN;          // B*HQ*N     = 65536
    float* AO = lb + (size_t)BB * HQH * NN;          // B*N*E      = 4194304

    dim3 blk(256);
    int M = BB * NN;  // 4096

    gemm128<<<dim3(EE / 128, M / 128), blk, 0, stream>>>(x, Wq, Qb, M, EE, EE);
    gemm128<<<dim3(KVE / 128, M / 128), blk, 0, stream>>>(x, Wk, Kb, M, EE, KVE);
    gemm128<<<dim3(KVE / 128, M / 128), blk, 0, stream>>>(x, Wv, Vb, M, EE, KVE);

    int ablocks = BB * HQH * (NN / 256);  // 256
    attn_ml<<<ablocks, blk, 0, stream>>>(Qb, Kb, mb, lb);
    attn_pv<<<ablocks, blk, 0, stream>>>(Qb, Kb, Vb, mb, lb, AO);
    attn_colsum<<<ablocks, blk, 0, stream>>>(Qb, Kb, mb, lb, aw);

    layernorm_inplace<<<BB * NN, blk, 0, stream>>>(AO, lng, lnb);
    gemm128<<<dim3(EE / 128, M / 128), blk, 0, stream>>>(AO, Wout, out, M, EE, EE);
}

// Round 2
// 782.719 us; speedup vs baseline: 3.5477x; 3.5477x over previous
//
#include <hip/hip_runtime.h>
#include <cmath>

#define BB 2
#define NN 2048
#define EE 1024
#define HQH 16
#define GG 4
#define DD 64
#define KVE 256

typedef short bf16x8 __attribute__((ext_vector_type(8)));
typedef float f32x4 __attribute__((ext_vector_type(4)));

__device__ __forceinline__ unsigned short f2bf(float f) {
    unsigned u = __float_as_uint(f);
    u += 0x7FFFu + ((u >> 16) & 1u);
    return (unsigned short)(u >> 16);
}

// ---------------------------------------------------------------------------
// Tiled fp32 GEMM: C[M x OC] = A[M x K] @ W[K x OC], row-major.
// 128x128 tile, K-step 16, 256 threads, 8x8 micro-tile. obf16 -> bf16 output.
// ---------------------------------------------------------------------------
__global__ __launch_bounds__(256)
void gemm128(const float* __restrict__ A, const float* __restrict__ W,
             void* __restrict__ C, int M, int K, int OC, int obf16) {
    __shared__ float As[16][132];   // transposed: As[k][m]
    __shared__ float Bs[16][132];
    int t = threadIdx.x;
    int tx = t & 15, ty = t >> 4;
    int n0 = blockIdx.x * 128;
    int m0 = blockIdx.y * 128;
    float acc[8][8];
#pragma unroll
    for (int i = 0; i < 8; ++i)
#pragma unroll
        for (int j = 0; j < 8; ++j) acc[i][j] = 0.f;

    for (int k0 = 0; k0 < K; k0 += 16) {
#pragma unroll
        for (int it = 0; it < 2; ++it) {
            int lin = t + it * 256;
            int r = lin >> 2;
            int kq = lin & 3;
            float4 a4 = *(const float4*)&A[(size_t)(m0 + r) * K + k0 + kq * 4];
            As[kq * 4 + 0][r] = a4.x;
            As[kq * 4 + 1][r] = a4.y;
            As[kq * 4 + 2][r] = a4.z;
            As[kq * 4 + 3][r] = a4.w;
        }
#pragma unroll
        for (int it = 0; it < 2; ++it) {
            int lin = t + it * 256;
            int r = lin >> 5;
            int c4 = lin & 31;
            float4 b4 = *(const float4*)&W[(size_t)(k0 + r) * OC + n0 + c4 * 4];
            *(float4*)&Bs[r][c4 * 4] = b4;
        }
        __syncthreads();
#pragma unroll
        for (int kk = 0; kk < 16; ++kk) {
            float a[8], br[8];
            *(float4*)&a[0] = *(const float4*)&As[kk][ty * 8];
            *(float4*)&a[4] = *(const float4*)&As[kk][ty * 8 + 4];
            *(float4*)&br[0] = *(const float4*)&Bs[kk][tx * 8];
            *(float4*)&br[4] = *(const float4*)&Bs[kk][tx * 8 + 4];
#pragma unroll
            for (int i = 0; i < 8; ++i)
#pragma unroll
                for (int j = 0; j < 8; ++j)
                    acc[i][j] = fmaf(a[i], br[j], acc[i][j]);
        }
        __syncthreads();
    }
    if (obf16) {
        unsigned short* Cb = (unsigned short*)C;
#pragma unroll
        for (int i = 0; i < 8; ++i) {
            bf16x8 pk;
#pragma unroll
            for (int j = 0; j < 8; ++j) pk[j] = (short)f2bf(acc[i][j]);
            *(bf16x8*)&Cb[(size_t)(m0 + ty * 8 + i) * OC + n0 + tx * 8] = pk;
        }
    } else {
        float* Cf = (float*)C;
#pragma unroll
        for (int i = 0; i < 8; ++i) {
            float4 o0 = {acc[i][0], acc[i][1], acc[i][2], acc[i][3]};
            float4 o1 = {acc[i][4], acc[i][5], acc[i][6], acc[i][7]};
            size_t base = (size_t)(m0 + ty * 8 + i) * OC + n0 + tx * 8;
            *(float4*)&Cf[base] = o0;
            *(float4*)&Cf[base + 4] = o1;
        }
    }
}

// ---------------------------------------------------------------------------
// Fused flash attention (MFMA bf16). Block = 128 q rows of one (b,hq).
// 4 waves x 2 row-tiles of 16. KV tiles of 64 staged in LDS (XOR-swizzled).
// V stored transposed. P round-trips through per-wave LDS to form A-frags.
// Writes AO (pre-LN, fp32), mbuf (row max of scaled scores), lbuf (1/l).
// ---------------------------------------------------------------------------
__global__ __launch_bounds__(256)
void flash_attn(const unsigned short* __restrict__ Qb,
                const unsigned short* __restrict__ Kb,
                const unsigned short* __restrict__ Vb,
                float* __restrict__ AO, float* __restrict__ mbuf,
                float* __restrict__ lbuf) {
    __shared__ __attribute__((aligned(16))) unsigned short sK[64 * 64];
    __shared__ __attribute__((aligned(16))) unsigned short sV[64 * 64];  // transposed [d][s]
    __shared__ __attribute__((aligned(16))) unsigned short sP[4 * 16 * 64];

    int blk = blockIdx.x;
    int ntile = blk & 15;            // N/128 = 16
    int bh = blk >> 4;
    int hq = bh & 15;
    int b = bh >> 4;
    int ih = hq >> 2, jh = hq & 3;
    int hm = jh * 4 + ih;
    int n0 = ntile * 128;
    int t = threadIdx.x;
    int lane = t & 63, w = t >> 6;
    int l15 = lane & 15, lg = lane >> 4;

    // Q A-fragments: rows n0 + w*32 + tt*16 + l15, k = lg*8 + h*32 + i
    bf16x8 qf[2][2];
#pragma unroll
    for (int tt = 0; tt < 2; ++tt)
#pragma unroll
        for (int h = 0; h < 2; ++h)
            qf[tt][h] = *(const bf16x8*)(Qb +
                (size_t)(b * NN + n0 + w * 32 + tt * 16 + l15) * EE + hq * DD + lg * 8 + h * 32);

    f32x4 o[2][4];
    float mrow[2][4], lrow[2][4];
#pragma unroll
    for (int tt = 0; tt < 2; ++tt)
#pragma unroll
        for (int i = 0; i < 4; ++i) {
            o[tt][i] = (f32x4){0.f, 0.f, 0.f, 0.f};
            mrow[tt][i] = -1e30f;
            lrow[tt][i] = 0.f;
        }

    char* pbase = (char*)sP + w * 2048;

    for (int s0 = 0; s0 < n0 + 128; s0 += 64) {
        // ---- stage K (row-major swz) and V (transposed swz) ----
#pragma unroll
        for (int it = 0; it < 2; ++it) {
            int lin = t + it * 256;
            int s = lin >> 3;
            int c8 = (lin & 7) * 8;
            bf16x8 kv = *(const bf16x8*)(Kb + (size_t)(b * NN + s0 + s) * KVE + ih * DD + c8);
            *(bf16x8*)((char*)sK + ((s * 128 + c8 * 2) ^ ((s & 7) << 4))) = kv;
            bf16x8 vv = *(const bf16x8*)(Vb + (size_t)(b * NN + s0 + s) * KVE + jh * DD + c8);
#pragma unroll
            for (int j = 0; j < 8; ++j) {
                int d = c8 + j;   // d&7 == j
                *(unsigned short*)((char*)sV + ((d * 128 + s * 2) ^ (j << 4))) =
                    (unsigned short)vv[j];
            }
        }
        __syncthreads();

        // ---- S = Q K^T ----
        f32x4 sf[2][4];
#pragma unroll
        for (int sub = 0; sub < 4; ++sub) {
            int row = sub * 16 + l15;
            int swz = (row & 7) << 4;
            bf16x8 k0 = *(const bf16x8*)((char*)sK + ((row * 128 + lg * 16) ^ swz));
            bf16x8 k1 = *(const bf16x8*)((char*)sK + ((row * 128 + lg * 16 + 64) ^ swz));
#pragma unroll
            for (int tt = 0; tt < 2; ++tt) {
                f32x4 z = {0.f, 0.f, 0.f, 0.f};
                z = __builtin_amdgcn_mfma_f32_16x16x32_bf16(qf[tt][0], k0, z, 0, 0, 0);
                sf[tt][sub] = __builtin_amdgcn_mfma_f32_16x16x32_bf16(qf[tt][1], k1, z, 0, 0, 0);
            }
        }

#pragma unroll
        for (int tt = 0; tt < 2; ++tt) {
            int nbase = n0 + w * 32 + tt * 16 + lg * 4;
            float mcur[4] = {-1e30f, -1e30f, -1e30f, -1e30f};
#pragma unroll
            for (int sub = 0; sub < 4; ++sub) {
                int sg = s0 + sub * 16 + l15;
#pragma unroll
                for (int r = 0; r < 4; ++r) {
                    float sc = sf[tt][sub][r] * 0.125f;
                    sc = (sg <= nbase + r) ? sc : -1e30f;
                    sf[tt][sub][r] = sc;
                    mcur[r] = fmaxf(mcur[r], sc);
                }
            }
#pragma unroll
            for (int r = 0; r < 4; ++r) {
                mcur[r] = fmaxf(mcur[r], __shfl_xor(mcur[r], 1));
                mcur[r] = fmaxf(mcur[r], __shfl_xor(mcur[r], 2));
                mcur[r] = fmaxf(mcur[r], __shfl_xor(mcur[r], 4));
                mcur[r] = fmaxf(mcur[r], __shfl_xor(mcur[r], 8));
            }
            float alpha[4], rs[4];
#pragma unroll
            for (int r = 0; r < 4; ++r) {
                float mnew = fmaxf(mrow[tt][r], mcur[r]);
                alpha[r] = __expf(mrow[tt][r] - mnew);
                mrow[tt][r] = mnew;
                rs[r] = 0.f;
            }
#pragma unroll
            for (int sub = 0; sub < 4; ++sub)
#pragma unroll
                for (int r = 0; r < 4; ++r) {
                    float p = __expf(sf[tt][sub][r] - mrow[tt][r]);
                    sf[tt][sub][r] = p;
                    rs[r] += p;
                }
#pragma unroll
            for (int r = 0; r < 4; ++r) {
                rs[r] += __shfl_xor(rs[r], 1);
                rs[r] += __shfl_xor(rs[r], 2);
                rs[r] += __shfl_xor(rs[r], 4);
                rs[r] += __shfl_xor(rs[r], 8);
                lrow[tt][r] = lrow[tt][r] * alpha[r] + rs[r];
            }
#pragma unroll
            for (int sd = 0; sd < 4; ++sd)
#pragma unroll
                for (int r = 0; r < 4; ++r) o[tt][sd][r] *= alpha[r];

            // P (16n x 64s) -> per-wave LDS, bf16, swizzled
#pragma unroll
            for (int sub = 0; sub < 4; ++sub)
#pragma unroll
                for (int r = 0; r < 4; ++r) {
                    int rr = lg * 4 + r;
                    int col = sub * 16 + l15;
                    *(unsigned short*)(pbase + ((rr * 128 + col * 2) ^ ((rr & 7) << 4))) =
                        f2bf(sf[tt][sub][r]);
                }
            int pswz = (l15 & 7) << 4;
            bf16x8 pa0 = *(const bf16x8*)(pbase + ((l15 * 128 + lg * 16) ^ pswz));
            bf16x8 pa1 = *(const bf16x8*)(pbase + ((l15 * 128 + lg * 16 + 64) ^ pswz));
#pragma unroll
            for (int sd = 0; sd < 4; ++sd) {
                int dr = sd * 16 + l15;
                int vswz = (dr & 7) << 4;
                bf16x8 v0 = *(const bf16x8*)((char*)sV + ((dr * 128 + lg * 16) ^ vswz));
                bf16x8 v1 = *(const bf16x8*)((char*)sV + ((dr * 128 + lg * 16 + 64) ^ vswz));
                o[tt][sd] = __builtin_amdgcn_mfma_f32_16x16x32_bf16(pa0, v0, o[tt][sd], 0, 0, 0);
                o[tt][sd] = __builtin_amdgcn_mfma_f32_16x16x32_bf16(pa1, v1, o[tt][sd], 0, 0, 0);
            }
        }
        __syncthreads();
    }

#pragma unroll
    for (int tt = 0; tt < 2; ++tt) {
        float inv[4];
#pragma unroll
        for (int r = 0; r < 4; ++r) inv[r] = 1.f / lrow[tt][r];
#pragma unroll
        for (int sd = 0; sd < 4; ++sd)
#pragma unroll
            for (int r = 0; r < 4; ++r) {
                int n = n0 + w * 32 + tt * 16 + lg * 4 + r;
                AO[(size_t)(b * NN + n) * EE + hm * DD + sd * 16 + l15] = o[tt][sd][r] * inv[r];
            }
        if (l15 == 0) {
#pragma unroll
            for (int r = 0; r < 4; ++r) {
                int n = n0 + w * 32 + tt * 16 + lg * 4 + r;
                mbuf[(size_t)bh * NN + n] = mrow[tt][r];
                lbuf[(size_t)bh * NN + n] = inv[r];
            }
        }
    }
}

// ---------------------------------------------------------------------------
// Column sums of probs via MFMA: A = K (M=s), B = Q^T (N=n).
// acc[s] += exp(score*scale - m_n) * linv_n summed over n; no atomics.
// ---------------------------------------------------------------------------
__global__ __launch_bounds__(256)
void colsum_mfma(const unsigned short* __restrict__ Qb,
                 const unsigned short* __restrict__ Kb,
                 const float* __restrict__ mbuf, const float* __restrict__ lbuf,
                 float* __restrict__ AW) {
    int blk = blockIdx.x;
    int stile = blk & 15;
    int bh = blk >> 4;
    int hq = bh & 15;
    int b = bh >> 4;
    int ih = hq >> 2, jh = hq & 3;
    int hm = jh * 4 + ih;
    int t = threadIdx.x;
    int lane = t & 63, w = t >> 6;
    int l15 = lane & 15, lg = lane >> 4;
    int sb = stile * 128 + w * 32;

    bf16x8 kf[2][2];
#pragma unroll
    for (int st = 0; st < 2; ++st)
#pragma unroll
        for (int h = 0; h < 2; ++h)
            kf[st][h] = *(const bf16x8*)(Kb +
                (size_t)(b * NN + sb + st * 16 + l15) * KVE + ih * DD + lg * 8 + h * 32);

    float acc[2][4] = {};
    int nstart = stile * 128;

    const unsigned short* qp0 = Qb + (size_t)(b * NN + nstart + l15) * EE + hq * DD + lg * 8;
    bf16x8 q0 = *(const bf16x8*)qp0;
    bf16x8 q1 = *(const bf16x8*)(qp0 + 32);
    float mv = mbuf[(size_t)bh * NN + nstart + l15];
    float li = lbuf[(size_t)bh * NN + nstart + l15];

    for (int nn0 = nstart; nn0 < NN; nn0 += 16) {
        bf16x8 cq0 = q0, cq1 = q1;
        float cmv = mv, cli = li;
        if (nn0 + 16 < NN) {
            const unsigned short* qp = Qb + (size_t)(b * NN + nn0 + 16 + l15) * EE + hq * DD + lg * 8;
            q0 = *(const bf16x8*)qp;
            q1 = *(const bf16x8*)(qp + 32);
            mv = mbuf[(size_t)bh * NN + nn0 + 16 + l15];
            li = lbuf[(size_t)bh * NN + nn0 + 16 + l15];
        }
        int n = nn0 + l15;
#pragma unroll
        for (int st = 0; st < 2; ++st) {
            f32x4 z = {0.f, 0.f, 0.f, 0.f};
            z = __builtin_amdgcn_mfma_f32_16x16x32_bf16(kf[st][0], cq0, z, 0, 0, 0);
            z = __builtin_amdgcn_mfma_f32_16x16x32_bf16(kf[st][1], cq1, z, 0, 0, 0);
#pragma unroll
            for (int r = 0; r < 4; ++r) {
                int s = sb + st * 16 + lg * 4 + r;
                float val = __expf(z[r] * 0.125f - cmv) * cli;
                acc[st][r] += (n >= s) ? val : 0.f;
            }
        }
    }
#pragma unroll
    for (int st = 0; st < 2; ++st)
#pragma unroll
        for (int r = 0; r < 4; ++r) {
            float a = acc[st][r];
            a += __shfl_xor(a, 1);
            a += __shfl_xor(a, 2);
            a += __shfl_xor(a, 4);
            a += __shfl_xor(a, 8);
            if (l15 == 0) {
                int s = sb + st * 16 + lg * 4 + r;
                AW[((size_t)b * NN + s) * HQH + hm] = a * (1.0f / NN);
            }
        }
}

// ---------------------------------------------------------------------------
// LayerNorm (in place) over last dim E=1024; one block per row.
// ---------------------------------------------------------------------------
__global__ __launch_bounds__(256)
void layernorm_inplace(float* __restrict__ X, const float* __restrict__ g,
                       const float* __restrict__ bt) {
    __shared__ float red[256];
    int row = blockIdx.x;
    int t = threadIdx.x;
    float* xp = X + (size_t)row * EE;
    float4 v = *(float4*)&xp[t * 4];
    red[t] = v.x + v.y + v.z + v.w;
    __syncthreads();
    for (int off = 128; off > 0; off >>= 1) {
        if (t < off) red[t] += red[t + off];
        __syncthreads();
    }
    float mu = red[0] * (1.f / EE);
    __syncthreads();
    float dx = v.x - mu, dy = v.y - mu, dz = v.z - mu, dw = v.w - mu;
    red[t] = dx * dx + dy * dy + dz * dz + dw * dw;
    __syncthreads();
    for (int off = 128; off > 0; off >>= 1) {
        if (t < off) red[t] += red[t + off];
        __syncthreads();
    }
    float rstd = rsqrtf(red[0] * (1.f / EE) + 1e-5f);
    float4 gg = *(const float4*)&g[t * 4];
    float4 bb = *(const float4*)&bt[t * 4];
    float4 o;
    o.x = dx * rstd * gg.x + bb.x;
    o.y = dy * rstd * gg.y + bb.y;
    o.z = dz * rstd * gg.z + bb.z;
    o.w = dw * rstd * gg.w + bb.w;
    *(float4*)&xp[t * 4] = o;
}

// ---------------------------------------------------------------------------
extern "C" void kernel_launch(void* const* d_in, const int* in_sizes, int n_in,
                              void* d_out, int out_size, void* d_ws, size_t ws_size,
                              hipStream_t stream) {
    const float* x    = (const float*)d_in[0];
    const float* Wq   = (const float*)d_in[1];
    const float* Wk   = (const float*)d_in[2];
    const float* Wv   = (const float*)d_in[3];
    const float* Wout = (const float*)d_in[4];
    const float* lng  = (const float*)d_in[5];
    const float* lnb  = (const float*)d_in[6];

    float* out = (float*)d_out;                      // [B][N][E]
    float* aw  = out + (size_t)BB * NN * EE;         // [B][N][HQ]

    unsigned short* Qb = (unsigned short*)d_ws;            // bf16 [B*N][E]
    unsigned short* Kb = Qb + (size_t)BB * NN * EE;        // bf16 [B*N][KVE]
    unsigned short* Vb = Kb + (size_t)BB * NN * KVE;       // bf16 [B*N][KVE]
    float* mb = (float*)(Vb + (size_t)BB * NN * KVE);      // [B*HQ][N]
    float* lb = mb + (size_t)BB * HQH * NN;                // [B*HQ][N] (1/l)
    float* AO = lb + (size_t)BB * HQH * NN;                // fp32 [B*N][E]

    dim3 blk(256);
    int M = BB * NN;  // 4096

    gemm128<<<dim3(EE / 128, M / 128), blk, 0, stream>>>(x, Wq, Qb, M, EE, EE, 1);
    gemm128<<<dim3(KVE / 128, M / 128), blk, 0, stream>>>(x, Wk, Kb, M, EE, KVE, 1);
    gemm128<<<dim3(KVE / 128, M / 128), blk, 0, stream>>>(x, Wv, Vb, M, EE, KVE, 1);

    int ablocks = BB * HQH * (NN / 128);  // 512
    flash_attn<<<ablocks, blk, 0, stream>>>(Qb, Kb, Vb, AO, mb, lb);
    colsum_mfma<<<ablocks, blk, 0, stream>>>(Qb, Kb, mb, lb, aw);

    layernorm_inplace<<<BB * NN, blk, 0, stream>>>(AO, lng, lnb);
    gemm128<<<dim3(EE / 128, M / 128), blk, 0, stream>>>(AO, Wout, out, M, EE, EE, 0);
}

// Round 3
// 350.802 us; speedup vs baseline: 7.9157x; 2.2312x over previous
//
#include <hip/hip_runtime.h>

#define BB 2
#define NN 2048
#define EE 1024
#define HQH 16
#define DD 64
#define KVE 256
#define QKVW 1536

typedef short bf16x8 __attribute__((ext_vector_type(8)));
typedef float f32x4 __attribute__((ext_vector_type(4)));
typedef unsigned short u16;

__device__ __forceinline__ u16 f2bf(float f) {
    unsigned u = __float_as_uint(f);
    u += 0x7FFFu + ((u >> 16) & 1u);
    return (u16)(u >> 16);
}
__device__ __forceinline__ float bf2f(u16 h) {
    return __uint_as_float(((unsigned)h) << 16);
}

#define GLOAD_LDS16(gp, lp) __builtin_amdgcn_global_load_lds( \
    (const __attribute__((address_space(1))) unsigned int*)(gp), \
    (__attribute__((address_space(3))) unsigned int*)(lp), 16, 0, 0)

// ---------------------------------------------------------------------------
// fp32 -> bf16 elementwise (8 elems/thread)
// ---------------------------------------------------------------------------
__global__ __launch_bounds__(256)
void conv_bf16(const float* __restrict__ in, u16* __restrict__ out) {
    int i = (blockIdx.x * 256 + threadIdx.x) * 8;
    float4 a = *(const float4*)&in[i];
    float4 b = *(const float4*)&in[i + 4];
    bf16x8 p;
    p[0] = f2bf(a.x); p[1] = f2bf(a.y); p[2] = f2bf(a.z); p[3] = f2bf(a.w);
    p[4] = f2bf(b.x); p[5] = f2bf(b.y); p[6] = f2bf(b.z); p[7] = f2bf(b.w);
    *(bf16x8*)&out[i] = p;
}

// ---------------------------------------------------------------------------
// Transposing fp32 -> bf16 convert: W[1024][Nc] -> WT[Nc][1024] (stride 1024).
// ---------------------------------------------------------------------------
__global__ __launch_bounds__(256)
void transp_bf16(const float* __restrict__ W, u16* __restrict__ WT, int Nc) {
    __shared__ float tile[32][33];
    int k0 = blockIdx.x * 32, n0 = blockIdx.y * 32;
    int tx = threadIdx.x & 31, ty = threadIdx.x >> 5;
#pragma unroll
    for (int i = 0; i < 4; ++i)
        tile[ty + i * 8][tx] = W[(size_t)(k0 + ty + i * 8) * Nc + n0 + tx];
    __syncthreads();
#pragma unroll
    for (int i = 0; i < 4; ++i)
        WT[(size_t)(n0 + ty + i * 8) * EE + k0 + tx] = f2bf(tile[tx][ty + i * 8]);
}

// ---------------------------------------------------------------------------
// MFMA bf16 GEMM, m97 structure: C[M][N] = A[M][K] @ BT[N][K]^T.
// 128x128 tile, BK=64, 4 waves (2x2), 64x64 per wave, 16x16x32 MFMA.
// global_load_lds(16B) staging, T2 swizzle (inverse-swz source + swz read).
// ---------------------------------------------------------------------------
__global__ __launch_bounds__(256)
void gemm_mfma(const u16* __restrict__ A, const u16* __restrict__ BT,
               void* __restrict__ C, int K, int ldc, int obf16) {
    __shared__ __attribute__((aligned(16))) u16 sA[128 * 64];
    __shared__ __attribute__((aligned(16))) u16 sB[128 * 64];
    int t = threadIdx.x;
    int lane = t & 63, w = t >> 6;
    int wr = w >> 1, wc = w & 1;
    int l15 = lane & 15, lg = lane >> 4;
    int m0 = blockIdx.y * 128, n0 = blockIdx.x * 128;

    f32x4 acc[4][4];
#pragma unroll
    for (int mi = 0; mi < 4; ++mi)
#pragma unroll
        for (int ni = 0; ni < 4; ++ni) acc[mi][ni] = (f32x4){0.f, 0.f, 0.f, 0.f};

    int srow = lane >> 3;                 // 0..7 (row within 8-row segment)
    int schunk = (lane & 7) ^ srow;       // inverse-swizzled 16B k-chunk
    const u16* ga = A + (size_t)(m0 + w * 32 + srow) * K + schunk * 8;
    const u16* gb = BT + (size_t)(n0 + w * 32 + srow) * K + schunk * 8;
    char* lA = (char*)sA + w * 4096;
    char* lB = (char*)sB + w * 4096;

    for (int k0 = 0; k0 < K; k0 += 64) {
#pragma unroll
        for (int i = 0; i < 4; ++i) {
            GLOAD_LDS16(ga + (size_t)i * 8 * K + k0, lA + i * 1024);
            GLOAD_LDS16(gb + (size_t)i * 8 * K + k0, lB + i * 1024);
        }
        __syncthreads();
#pragma unroll
        for (int ks = 0; ks < 2; ++ks) {
            bf16x8 af[4], bfr[4];
#pragma unroll
            for (int mi = 0; mi < 4; ++mi) {
                int row = wr * 64 + mi * 16 + l15;
                af[mi] = *(const bf16x8*)((char*)sA +
                    ((row * 128 + lg * 16 + ks * 64) ^ ((row & 7) << 4)));
            }
#pragma unroll
            for (int ni = 0; ni < 4; ++ni) {
                int row = wc * 64 + ni * 16 + l15;
                bfr[ni] = *(const bf16x8*)((char*)sB +
                    ((row * 128 + lg * 16 + ks * 64) ^ ((row & 7) << 4)));
            }
#pragma unroll
            for (int mi = 0; mi < 4; ++mi)
#pragma unroll
                for (int ni = 0; ni < 4; ++ni)
                    acc[mi][ni] = __builtin_amdgcn_mfma_f32_16x16x32_bf16(
                        af[mi], bfr[ni], acc[mi][ni], 0, 0, 0);
        }
        __syncthreads();
    }

#pragma unroll
    for (int mi = 0; mi < 4; ++mi) {
        int rbase = m0 + wr * 64 + mi * 16 + lg * 4;
#pragma unroll
        for (int ni = 0; ni < 4; ++ni) {
            int col = n0 + wc * 64 + ni * 16 + l15;
            if (obf16) {
                u16* Cb = (u16*)C;
#pragma unroll
                for (int r = 0; r < 4; ++r)
                    Cb[(size_t)(rbase + r) * ldc + col] = f2bf(acc[mi][ni][r]);
            } else {
                float* Cf = (float*)C;
#pragma unroll
                for (int r = 0; r < 4; ++r)
                    Cf[(size_t)(rbase + r) * ldc + col] = acc[mi][ni][r];
            }
        }
    }
}

// ---------------------------------------------------------------------------
// Fused flash attention (MFMA bf16) reading packed QKV (stride 1536).
// Block = 128 q rows of one (b,hq). Writes AO bf16, mbuf, lbuf(=1/l).
// ---------------------------------------------------------------------------
__global__ __launch_bounds__(256)
void flash_attn(const u16* __restrict__ QKV, u16* __restrict__ AOb,
                float* __restrict__ mbuf, float* __restrict__ lbuf) {
    __shared__ __attribute__((aligned(16))) u16 sK[64 * 64];
    __shared__ __attribute__((aligned(16))) u16 sV[64 * 64];  // transposed [d][s]
    __shared__ __attribute__((aligned(16))) u16 sP[4 * 16 * 64];

    int blk = blockIdx.x;
    int ntile = blk & 15;            // N/128 = 16
    int bh = blk >> 4;
    int hq = bh & 15;
    int b = bh >> 4;
    int ih = hq >> 2, jh = hq & 3;
    int hm = jh * 4 + ih;
    int n0 = ntile * 128;
    int t = threadIdx.x;
    int lane = t & 63, w = t >> 6;
    int l15 = lane & 15, lg = lane >> 4;

    bf16x8 qf[2][2];
#pragma unroll
    for (int tt = 0; tt < 2; ++tt)
#pragma unroll
        for (int h = 0; h < 2; ++h)
            qf[tt][h] = *(const bf16x8*)(QKV +
                (size_t)(b * NN + n0 + w * 32 + tt * 16 + l15) * QKVW + hq * DD + lg * 8 + h * 32);

    f32x4 o[2][4];
    float mrow[2][4], lrow[2][4];
#pragma unroll
    for (int tt = 0; tt < 2; ++tt)
#pragma unroll
        for (int i = 0; i < 4; ++i) {
            o[tt][i] = (f32x4){0.f, 0.f, 0.f, 0.f};
            mrow[tt][i] = -1e30f;
            lrow[tt][i] = 0.f;
        }

    char* pbase = (char*)sP + w * 2048;

    for (int s0 = 0; s0 < n0 + 128; s0 += 64) {
#pragma unroll
        for (int it = 0; it < 2; ++it) {
            int lin = t + it * 256;
            int s = lin >> 3;
            int c8 = (lin & 7) * 8;
            bf16x8 kv = *(const bf16x8*)(QKV + (size_t)(b * NN + s0 + s) * QKVW + EE + ih * DD + c8);
            *(bf16x8*)((char*)sK + ((s * 128 + c8 * 2) ^ ((s & 7) << 4))) = kv;
            bf16x8 vv = *(const bf16x8*)(QKV + (size_t)(b * NN + s0 + s) * QKVW + EE + KVE + jh * DD + c8);
#pragma unroll
            for (int j = 0; j < 8; ++j) {
                int d = c8 + j;   // d&7 == j
                *(u16*)((char*)sV + ((d * 128 + s * 2) ^ (j << 4))) = (u16)vv[j];
            }
        }
        __syncthreads();

        f32x4 sf[2][4];
#pragma unroll
        for (int sub = 0; sub < 4; ++sub) {
            int row = sub * 16 + l15;
            int swz = (row & 7) << 4;
            bf16x8 k0 = *(const bf16x8*)((char*)sK + ((row * 128 + lg * 16) ^ swz));
            bf16x8 k1 = *(const bf16x8*)((char*)sK + ((row * 128 + lg * 16 + 64) ^ swz));
#pragma unroll
            for (int tt = 0; tt < 2; ++tt) {
                f32x4 z = {0.f, 0.f, 0.f, 0.f};
                z = __builtin_amdgcn_mfma_f32_16x16x32_bf16(qf[tt][0], k0, z, 0, 0, 0);
                sf[tt][sub] = __builtin_amdgcn_mfma_f32_16x16x32_bf16(qf[tt][1], k1, z, 0, 0, 0);
            }
        }

#pragma unroll
        for (int tt = 0; tt < 2; ++tt) {
            int nbase = n0 + w * 32 + tt * 16 + lg * 4;
            float mcur[4] = {-1e30f, -1e30f, -1e30f, -1e30f};
#pragma unroll
            for (int sub = 0; sub < 4; ++sub) {
                int sg = s0 + sub * 16 + l15;
#pragma unroll
                for (int r = 0; r < 4; ++r) {
                    float sc = sf[tt][sub][r] * 0.125f;
                    sc = (sg <= nbase + r) ? sc : -1e30f;
                    sf[tt][sub][r] = sc;
                    mcur[r] = fmaxf(mcur[r], sc);
                }
            }
#pragma unroll
            for (int r = 0; r < 4; ++r) {
                mcur[r] = fmaxf(mcur[r], __shfl_xor(mcur[r], 1));
                mcur[r] = fmaxf(mcur[r], __shfl_xor(mcur[r], 2));
                mcur[r] = fmaxf(mcur[r], __shfl_xor(mcur[r], 4));
                mcur[r] = fmaxf(mcur[r], __shfl_xor(mcur[r], 8));
            }
            float alpha[4], rs[4];
#pragma unroll
            for (int r = 0; r < 4; ++r) {
                float mnew = fmaxf(mrow[tt][r], mcur[r]);
                alpha[r] = __expf(mrow[tt][r] - mnew);
                mrow[tt][r] = mnew;
                rs[r] = 0.f;
            }
#pragma unroll
            for (int sub = 0; sub < 4; ++sub)
#pragma unroll
                for (int r = 0; r < 4; ++r) {
                    float p = __expf(sf[tt][sub][r] - mrow[tt][r]);
                    sf[tt][sub][r] = p;
                    rs[r] += p;
                }
#pragma unroll
            for (int r = 0; r < 4; ++r) {
                rs[r] += __shfl_xor(rs[r], 1);
                rs[r] += __shfl_xor(rs[r], 2);
                rs[r] += __shfl_xor(rs[r], 4);
                rs[r] += __shfl_xor(rs[r], 8);
                lrow[tt][r] = lrow[tt][r] * alpha[r] + rs[r];
            }
#pragma unroll
            for (int sd = 0; sd < 4; ++sd)
#pragma unroll
                for (int r = 0; r < 4; ++r) o[tt][sd][r] *= alpha[r];

#pragma unroll
            for (int sub = 0; sub < 4; ++sub)
#pragma unroll
                for (int r = 0; r < 4; ++r) {
                    int rr = lg * 4 + r;
                    int col = sub * 16 + l15;
                    *(u16*)(pbase + ((rr * 128 + col * 2) ^ ((rr & 7) << 4))) =
                        f2bf(sf[tt][sub][r]);
                }
            int pswz = (l15 & 7) << 4;
            bf16x8 pa0 = *(const bf16x8*)(pbase + ((l15 * 128 + lg * 16) ^ pswz));
            bf16x8 pa1 = *(const bf16x8*)(pbase + ((l15 * 128 + lg * 16 + 64) ^ pswz));
#pragma unroll
            for (int sd = 0; sd < 4; ++sd) {
                int dr = sd * 16 + l15;
                int vswz = (dr & 7) << 4;
                bf16x8 v0 = *(const bf16x8*)((char*)sV + ((dr * 128 + lg * 16) ^ vswz));
                bf16x8 v1 = *(const bf16x8*)((char*)sV + ((dr * 128 + lg * 16 + 64) ^ vswz));
                o[tt][sd] = __builtin_amdgcn_mfma_f32_16x16x32_bf16(pa0, v0, o[tt][sd], 0, 0, 0);
                o[tt][sd] = __builtin_amdgcn_mfma_f32_16x16x32_bf16(pa1, v1, o[tt][sd], 0, 0, 0);
            }
        }
        __syncthreads();
    }

#pragma unroll
    for (int tt = 0; tt < 2; ++tt) {
        float inv[4];
#pragma unroll
        for (int r = 0; r < 4; ++r) inv[r] = 1.f / lrow[tt][r];
#pragma unroll
        for (int sd = 0; sd < 4; ++sd)
#pragma unroll
            for (int r = 0; r < 4; ++r) {
                int n = n0 + w * 32 + tt * 16 + lg * 4 + r;
                AOb[(size_t)(b * NN + n) * EE + hm * DD + sd * 16 + l15] =
                    f2bf(o[tt][sd][r] * inv[r]);
            }
        if (l15 == 0) {
#pragma unroll
            for (int r = 0; r < 4; ++r) {
                int n = n0 + w * 32 + tt * 16 + lg * 4 + r;
                mbuf[(size_t)bh * NN + n] = mrow[tt][r];
                lbuf[(size_t)bh * NN + n] = inv[r];
            }
        }
    }
}

// ---------------------------------------------------------------------------
// Column sums of probs via MFMA (A = K rows, B = Q^T), no atomics.
// ---------------------------------------------------------------------------
__global__ __launch_bounds__(256)
void colsum_mfma(const u16* __restrict__ QKV,
                 const float* __restrict__ mbuf, const float* __restrict__ lbuf,
                 float* __restrict__ AW) {
    int blk = blockIdx.x;
    int stile = blk & 15;
    int bh = blk >> 4;
    int hq = bh & 15;
    int b = bh >> 4;
    int ih = hq >> 2, jh = hq & 3;
    int hm = jh * 4 + ih;
    int t = threadIdx.x;
    int lane = t & 63, w = t >> 6;
    int l15 = lane & 15, lg = lane >> 4;
    int sb = stile * 128 + w * 32;

    bf16x8 kf[2][2];
#pragma unroll
    for (int st = 0; st < 2; ++st)
#pragma unroll
        for (int h = 0; h < 2; ++h)
            kf[st][h] = *(const bf16x8*)(QKV +
                (size_t)(b * NN + sb + st * 16 + l15) * QKVW + EE + ih * DD + lg * 8 + h * 32);

    float acc[2][4] = {};
    int nstart = stile * 128;

    const u16* qp0 = QKV + (size_t)(b * NN + nstart + l15) * QKVW + hq * DD + lg * 8;
    bf16x8 q0 = *(const bf16x8*)qp0;
    bf16x8 q1 = *(const bf16x8*)(qp0 + 32);
    float mv = mbuf[(size_t)bh * NN + nstart + l15];
    float li = lbuf[(size_t)bh * NN + nstart + l15];

    for (int nn0 = nstart; nn0 < NN; nn0 += 16) {
        bf16x8 cq0 = q0, cq1 = q1;
        float cmv = mv, cli = li;
        if (nn0 + 16 < NN) {
            const u16* qp = QKV + (size_t)(b * NN + nn0 + 16 + l15) * QKVW + hq * DD + lg * 8;
            q0 = *(const bf16x8*)qp;
            q1 = *(const bf16x8*)(qp + 32);
            mv = mbuf[(size_t)bh * NN + nn0 + 16 + l15];
            li = lbuf[(size_t)bh * NN + nn0 + 16 + l15];
        }
        int n = nn0 + l15;
#pragma unroll
        for (int st = 0; st < 2; ++st) {
            f32x4 z = {0.f, 0.f, 0.f, 0.f};
            z = __builtin_amdgcn_mfma_f32_16x16x32_bf16(kf[st][0], cq0, z, 0, 0, 0);
            z = __builtin_amdgcn_mfma_f32_16x16x32_bf16(kf[st][1], cq1, z, 0, 0, 0);
#pragma unroll
            for (int r = 0; r < 4; ++r) {
                int s = sb + st * 16 + lg * 4 + r;
                float val = __expf(z[r] * 0.125f - cmv) * cli;
                acc[st][r] += (n >= s) ? val : 0.f;
            }
        }
    }
#pragma unroll
    for (int st = 0; st < 2; ++st)
#pragma unroll
        for (int r = 0; r < 4; ++r) {
            float a = acc[st][r];
            a += __shfl_xor(a, 1);
            a += __shfl_xor(a, 2);
            a += __shfl_xor(a, 4);
            a += __shfl_xor(a, 8);
            if (l15 == 0) {
                int s = sb + st * 16 + lg * 4 + r;
                AW[((size_t)b * NN + s) * HQH + hm] = a * (1.0f / NN);
            }
        }
}

// ---------------------------------------------------------------------------
// LayerNorm in place over bf16 rows of length E=1024.
// ---------------------------------------------------------------------------
__global__ __launch_bounds__(256)
void layernorm_bf16(u16* __restrict__ X, const float* __restrict__ g,
                    const float* __restrict__ bt) {
    __shared__ float red[256];
    int row = blockIdx.x;
    int t = threadIdx.x;
    u16* xp = X + (size_t)row * EE;
    ushort4 v = *(ushort4*)&xp[t * 4];
    float x0 = bf2f(v.x), x1 = bf2f(v.y), x2 = bf2f(v.z), x3 = bf2f(v.w);
    red[t] = x0 + x1 + x2 + x3;
    __syncthreads();
    for (int off = 128; off > 0; off >>= 1) {
        if (t < off) red[t] += red[t + off];
        __syncthreads();
    }
    float mu = red[0] * (1.f / EE);
    __syncthreads();
    float d0 = x0 - mu, d1 = x1 - mu, d2 = x2 - mu, d3 = x3 - mu;
    red[t] = d0 * d0 + d1 * d1 + d2 * d2 + d3 * d3;
    __syncthreads();
    for (int off = 128; off > 0; off >>= 1) {
        if (t < off) red[t] += red[t + off];
        __syncthreads();
    }
    float rstd = rsqrtf(red[0] * (1.f / EE) + 1e-5f);
    float4 gg = *(const float4*)&g[t * 4];
    float4 bb = *(const float4*)&bt[t * 4];
    ushort4 o;
    o.x = f2bf(d0 * rstd * gg.x + bb.x);
    o.y = f2bf(d1 * rstd * gg.y + bb.y);
    o.z = f2bf(d2 * rstd * gg.z + bb.z);
    o.w = f2bf(d3 * rstd * gg.w + bb.w);
    *(ushort4*)&xp[t * 4] = o;
}

// ---------------------------------------------------------------------------
extern "C" void kernel_launch(void* const* d_in, const int* in_sizes, int n_in,
                              void* d_out, int out_size, void* d_ws, size_t ws_size,
                              hipStream_t stream) {
    const float* x    = (const float*)d_in[0];
    const float* Wq   = (const float*)d_in[1];
    const float* Wk   = (const float*)d_in[2];
    const float* Wv   = (const float*)d_in[3];
    const float* Wout = (const float*)d_in[4];
    const float* lng  = (const float*)d_in[5];
    const float* lnb  = (const float*)d_in[6];

    float* out = (float*)d_out;                      // [B][N][E]
    float* aw  = out + (size_t)BB * NN * EE;         // [B][N][HQ]

    u16* Xb    = (u16*)d_ws;                         // [4096][1024]
    u16* QKVb  = Xb + (size_t)BB * NN * EE;          // [4096][1536]
    u16* WqkvT = QKVb + (size_t)BB * NN * QKVW;      // [1536][1024]
    u16* WoutT = WqkvT + (size_t)QKVW * EE;          // [1024][1024]
    u16* AOb   = WoutT + (size_t)EE * EE;            // [4096][1024]
    float* mb  = (float*)(AOb + (size_t)BB * NN * EE);
    float* lb  = mb + (size_t)BB * HQH * NN;

    dim3 blk(256);

    conv_bf16<<<BB * NN * EE / 2048, blk, 0, stream>>>(x, Xb);
    transp_bf16<<<dim3(32, 32), blk, 0, stream>>>(Wq, WqkvT, EE);
    transp_bf16<<<dim3(32, 8), blk, 0, stream>>>(Wk, WqkvT + (size_t)EE * EE, KVE);
    transp_bf16<<<dim3(32, 8), blk, 0, stream>>>(Wv, WqkvT + (size_t)(EE + KVE) * EE, KVE);
    transp_bf16<<<dim3(32, 32), blk, 0, stream>>>(Wout, WoutT, EE);

    gemm_mfma<<<dim3(QKVW / 128, BB * NN / 128), blk, 0, stream>>>(
        Xb, WqkvT, QKVb, EE, QKVW, 1);

    int ablocks = BB * HQH * (NN / 128);  // 512
    flash_attn<<<ablocks, blk, 0, stream>>>(QKVb, AOb, mb, lb);
    colsum_mfma<<<ablocks, blk, 0, stream>>>(QKVb, mb, lb, aw);

    layernorm_bf16<<<BB * NN, blk, 0, stream>>>(AOb, lng, lnb);

    gemm_mfma<<<dim3(EE / 128, BB * NN / 128), blk, 0, stream>>>(
        AOb, WoutT, out, EE, EE, 0);
}

// Round 4
// 315.830 us; speedup vs baseline: 8.7922x; 1.1107x over previous
//
#include <hip/hip_runtime.h>

#define BB 2
#define NN 2048
#define EE 1024
#define HQH 16
#define DD 64
#define KVE 256
#define QKVW 1536

typedef short bf16x8 __attribute__((ext_vector_type(8)));
typedef float f32x4 __attribute__((ext_vector_type(4)));
typedef unsigned short u16;
typedef unsigned int u32;

#if __has_builtin(__builtin_amdgcn_exp2f)
#define EXP2(x) __builtin_amdgcn_exp2f(x)
#else
#define EXP2(x) exp2f(x)
#endif

// softmax scale 1/sqrt(64) folded with log2(e) so we can use raw exp2
#define QSCALE 0.18033688011112042f

__device__ __forceinline__ u16 f2bf(float f) {
    unsigned u = __float_as_uint(f);
    u += 0x7FFFu + ((u >> 16) & 1u);
    return (u16)(u >> 16);
}
__device__ __forceinline__ float bf2f(u16 h) {
    return __uint_as_float(((unsigned)h) << 16);
}

#define GLOAD_LDS16(gp, lp) __builtin_amdgcn_global_load_lds( \
    (const __attribute__((address_space(1))) unsigned int*)(gp), \
    (__attribute__((address_space(3))) unsigned int*)(lp), 16, 0, 0)

// 8x8 bf16 transpose across 8 consecutive lanes (q = lane&7).
// In: lane q holds M[q][0..7]; out: lane q holds M[0..7][q].
__device__ __forceinline__ bf16x8 xpose8(bf16x8 v, int q) {
    union { bf16x8 v; u32 r[4]; } u_;
    u_.v = v;
    u32 r0 = u_.r[0], r1 = u_.r[1], r2 = u_.r[2], r3 = u_.r[3];
    u32 x, y, t0;
    x = (q & 4) ? r0 : r2;  y = (q & 4) ? r1 : r3;
    x = __shfl_xor(x, 4);   y = __shfl_xor(y, 4);
    if (q & 4) { r0 = x; r1 = y; } else { r2 = x; r3 = y; }
    x = (q & 2) ? r0 : r1;  y = (q & 2) ? r2 : r3;
    x = __shfl_xor(x, 2);   y = __shfl_xor(y, 2);
    if (q & 2) { r0 = x; r2 = y; } else { r1 = x; r3 = y; }
    t0 = __shfl_xor(r0, 1); r0 = (q & 1) ? ((t0 >> 16) | (r0 & 0xFFFF0000u)) : ((r0 & 0xFFFFu) | (t0 << 16));
    t0 = __shfl_xor(r1, 1); r1 = (q & 1) ? ((t0 >> 16) | (r1 & 0xFFFF0000u)) : ((r1 & 0xFFFFu) | (t0 << 16));
    t0 = __shfl_xor(r2, 1); r2 = (q & 1) ? ((t0 >> 16) | (r2 & 0xFFFF0000u)) : ((r2 & 0xFFFFu) | (t0 << 16));
    t0 = __shfl_xor(r3, 1); r3 = (q & 1) ? ((t0 >> 16) | (r3 & 0xFFFF0000u)) : ((r3 & 0xFFFFu) | (t0 << 16));
    u_.r[0] = r0; u_.r[1] = r1; u_.r[2] = r2; u_.r[3] = r3;
    return u_.v;
}

// ---------------------------------------------------------------------------
// fp32 -> bf16 elementwise (8 elems/thread)
// ---------------------------------------------------------------------------
__global__ __launch_bounds__(256)
void conv_bf16(const float* __restrict__ in, u16* __restrict__ out) {
    int i = (blockIdx.x * 256 + threadIdx.x) * 8;
    float4 a = *(const float4*)&in[i];
    float4 b = *(const float4*)&in[i + 4];
    bf16x8 p;
    p[0] = f2bf(a.x); p[1] = f2bf(a.y); p[2] = f2bf(a.z); p[3] = f2bf(a.w);
    p[4] = f2bf(b.x); p[5] = f2bf(b.y); p[6] = f2bf(b.z); p[7] = f2bf(b.w);
    *(bf16x8*)&out[i] = p;
}

// ---------------------------------------------------------------------------
// Transposing fp32 -> bf16 convert: W[1024][Nc] -> WT[Nc][1024] (stride 1024).
// ---------------------------------------------------------------------------
__global__ __launch_bounds__(256)
void transp_bf16(const float* __restrict__ W, u16* __restrict__ WT, int Nc) {
    __shared__ float tile[32][33];
    int k0 = blockIdx.x * 32, n0 = blockIdx.y * 32;
    int tx = threadIdx.x & 31, ty = threadIdx.x >> 5;
#pragma unroll
    for (int i = 0; i < 4; ++i)
        tile[ty + i * 8][tx] = W[(size_t)(k0 + ty + i * 8) * Nc + n0 + tx];
    __syncthreads();
#pragma unroll
    for (int i = 0; i < 4; ++i)
        WT[(size_t)(n0 + ty + i * 8) * EE + k0 + tx] = f2bf(tile[tx][ty + i * 8]);
}

// ---------------------------------------------------------------------------
// MFMA bf16 GEMM (m97 structure). Epilogue scales cols < nq by qscale.
// ---------------------------------------------------------------------------
__global__ __launch_bounds__(256)
void gemm_mfma(const u16* __restrict__ A, const u16* __restrict__ BT,
               void* __restrict__ C, int K, int ldc, int obf16,
               float qscale, int nq) {
    __shared__ __attribute__((aligned(16))) u16 sA[128 * 64];
    __shared__ __attribute__((aligned(16))) u16 sB[128 * 64];
    int t = threadIdx.x;
    int lane = t & 63, w = t >> 6;
    int wr = w >> 1, wc = w & 1;
    int l15 = lane & 15, lg = lane >> 4;
    int m0 = blockIdx.y * 128, n0 = blockIdx.x * 128;

    f32x4 acc[4][4];
#pragma unroll
    for (int mi = 0; mi < 4; ++mi)
#pragma unroll
        for (int ni = 0; ni < 4; ++ni) acc[mi][ni] = (f32x4){0.f, 0.f, 0.f, 0.f};

    int srow = lane >> 3;
    int schunk = (lane & 7) ^ srow;
    const u16* ga = A + (size_t)(m0 + w * 32 + srow) * K + schunk * 8;
    const u16* gb = BT + (size_t)(n0 + w * 32 + srow) * K + schunk * 8;
    char* lA = (char*)sA + w * 4096;
    char* lB = (char*)sB + w * 4096;

    for (int k0 = 0; k0 < K; k0 += 64) {
#pragma unroll
        for (int i = 0; i < 4; ++i) {
            GLOAD_LDS16(ga + (size_t)i * 8 * K + k0, lA + i * 1024);
            GLOAD_LDS16(gb + (size_t)i * 8 * K + k0, lB + i * 1024);
        }
        __syncthreads();
#pragma unroll
        for (int ks = 0; ks < 2; ++ks) {
            bf16x8 af[4], bfr[4];
#pragma unroll
            for (int mi = 0; mi < 4; ++mi) {
                int row = wr * 64 + mi * 16 + l15;
                af[mi] = *(const bf16x8*)((char*)sA +
                    ((row * 128 + lg * 16 + ks * 64) ^ ((row & 7) << 4)));
            }
#pragma unroll
            for (int ni = 0; ni < 4; ++ni) {
                int row = wc * 64 + ni * 16 + l15;
                bfr[ni] = *(const bf16x8*)((char*)sB +
                    ((row * 128 + lg * 16 + ks * 64) ^ ((row & 7) << 4)));
            }
#pragma unroll
            for (int mi = 0; mi < 4; ++mi)
#pragma unroll
                for (int ni = 0; ni < 4; ++ni)
                    acc[mi][ni] = __builtin_amdgcn_mfma_f32_16x16x32_bf16(
                        af[mi], bfr[ni], acc[mi][ni], 0, 0, 0);
        }
        __syncthreads();
    }

#pragma unroll
    for (int mi = 0; mi < 4; ++mi) {
        int rbase = m0 + wr * 64 + mi * 16 + lg * 4;
#pragma unroll
        for (int ni = 0; ni < 4; ++ni) {
            int col = n0 + wc * 64 + ni * 16 + l15;
            float sc = (col < nq) ? qscale : 1.0f;
            if (obf16) {
                u16* Cb = (u16*)C;
#pragma unroll
                for (int r = 0; r < 4; ++r)
                    Cb[(size_t)(rbase + r) * ldc + col] = f2bf(acc[mi][ni][r] * sc);
            } else {
                float* Cf = (float*)C;
#pragma unroll
                for (int r = 0; r < 4; ++r)
                    Cf[(size_t)(rbase + r) * ldc + col] = acc[mi][ni][r] * sc;
            }
        }
    }
}

// ---------------------------------------------------------------------------
// Fused flash attention (MFMA bf16), packed QKV (stride 1536), Q pre-scaled.
// Block handles TWO q-tiles (pk and 15-pk) of 128 rows -> perfectly balanced
// (34 KV-tiles per block). Grid = 256. Register prefetch of next K/V tile;
// V transposed in-registers (xpose8) -> vectorized swizzled LDS stores.
// ---------------------------------------------------------------------------
__global__ __launch_bounds__(256)
void flash_attn(const u16* __restrict__ QKV, u16* __restrict__ AOb,
                float* __restrict__ mbuf, float* __restrict__ lbuf) {
    __shared__ __attribute__((aligned(16))) u16 sK[64 * 64];
    __shared__ __attribute__((aligned(16))) u16 sV[64 * 64];  // transposed [d][s]
    __shared__ __attribute__((aligned(16))) u16 sP[4 * 16 * 64];

    int blk = blockIdx.x;
    int pk = blk & 7;
    int bh = blk >> 3;               // (b, hq)
    int hq = bh & 15;
    int b = bh >> 4;
    int ih = hq >> 2, jh = hq & 3;
    int hm = jh * 4 + ih;
    int t = threadIdx.x;
    int lane = t & 63, w = t >> 6;
    int l15 = lane & 15, lg = lane >> 4;
    int q8 = t & 7;

    const u16* Kg = QKV + (size_t)b * NN * QKVW + EE + ih * DD;
    const u16* Vg = QKV + (size_t)b * NN * QKVW + EE + KVE + jh * DD;
    char* pbase = (char*)sP + w * 2048;

    for (int half = 0; half < 2; ++half) {
        int ntile = half ? (15 - pk) : pk;
        int n0 = ntile * 128;

        bf16x8 qf[2][2];
#pragma unroll
        for (int tt = 0; tt < 2; ++tt)
#pragma unroll
            for (int h = 0; h < 2; ++h)
                qf[tt][h] = *(const bf16x8*)(QKV +
                    (size_t)(b * NN + n0 + w * 32 + tt * 16 + l15) * QKVW + hq * DD + lg * 8 + h * 32);

        f32x4 o[2][4];
        float mrow[2][4], lrow[2][4];
#pragma unroll
        for (int tt = 0; tt < 2; ++tt)
#pragma unroll
            for (int i = 0; i < 4; ++i) {
                o[tt][i] = (f32x4){0.f, 0.f, 0.f, 0.f};
                mrow[tt][i] = -1e30f;
                lrow[tt][i] = 0.f;
            }

        int send = n0 + 128;
        bf16x8 kreg[2], vreg[2];
        // prologue loads (tile s0 = 0)
#pragma unroll
        for (int it = 0; it < 2; ++it) {
            int lin = t + it * 256;
            kreg[it] = *(const bf16x8*)(Kg + (size_t)(lin >> 3) * QKVW + (lin & 7) * 8);
            vreg[it] = *(const bf16x8*)(Vg + (size_t)((lin >> 6) * 8 + q8) * QKVW + ((lin >> 3) & 7) * 8);
        }

        for (int s0 = 0; s0 < send; s0 += 64) {
            // ---- stage staged regs into LDS ----
#pragma unroll
            for (int it = 0; it < 2; ++it) {
                int lin = t + it * 256;
                int sk = lin >> 3, c8k = (lin & 7) * 8;
                *(bf16x8*)((char*)sK + ((sk * 128 + c8k * 2) ^ ((sk & 7) << 4))) = kreg[it];
                bf16x8 vt = xpose8(vreg[it], q8);
                int d = ((lin >> 3) & 7) * 8 + q8;
                int sbase = (lin >> 6) * 8;
                *(bf16x8*)((char*)sV + ((d * 128 + sbase * 2) ^ (q8 << 4))) = vt;
            }
            // ---- prefetch next tile into regs ----
            if (s0 + 64 < send) {
#pragma unroll
                for (int it = 0; it < 2; ++it) {
                    int lin = t + it * 256;
                    kreg[it] = *(const bf16x8*)(Kg + (size_t)(s0 + 64 + (lin >> 3)) * QKVW + (lin & 7) * 8);
                    vreg[it] = *(const bf16x8*)(Vg + (size_t)(s0 + 64 + (lin >> 6) * 8 + q8) * QKVW + ((lin >> 3) & 7) * 8);
                }
            }
            __syncthreads();

            // ---- S = Q K^T (pre-scaled) ----
            f32x4 sf[2][4];
#pragma unroll
            for (int sub = 0; sub < 4; ++sub) {
                int row = sub * 16 + l15;
                int swz = (row & 7) << 4;
                bf16x8 k0 = *(const bf16x8*)((char*)sK + ((row * 128 + lg * 16) ^ swz));
                bf16x8 k1 = *(const bf16x8*)((char*)sK + ((row * 128 + lg * 16 + 64) ^ swz));
#pragma unroll
                for (int tt = 0; tt < 2; ++tt) {
                    f32x4 z = {0.f, 0.f, 0.f, 0.f};
                    z = __builtin_amdgcn_mfma_f32_16x16x32_bf16(qf[tt][0], k0, z, 0, 0, 0);
                    sf[tt][sub] = __builtin_amdgcn_mfma_f32_16x16x32_bf16(qf[tt][1], k1, z, 0, 0, 0);
                }
            }

#pragma unroll
            for (int tt = 0; tt < 2; ++tt) {
                int nb_min = n0 + w * 32 + tt * 16;
                int nbase = nb_min + lg * 4;
                float mcur[4] = {-1e30f, -1e30f, -1e30f, -1e30f};
                if (s0 + 63 > nb_min) {   // diagonal tile: apply causal mask
#pragma unroll
                    for (int sub = 0; sub < 4; ++sub) {
                        int sg = s0 + sub * 16 + l15;
#pragma unroll
                        for (int r = 0; r < 4; ++r) {
                            float sc = sf[tt][sub][r];
                            sc = (sg <= nbase + r) ? sc : -1e30f;
                            sf[tt][sub][r] = sc;
                            mcur[r] = fmaxf(mcur[r], sc);
                        }
                    }
                } else {
#pragma unroll
                    for (int sub = 0; sub < 4; ++sub)
#pragma unroll
                        for (int r = 0; r < 4; ++r)
                            mcur[r] = fmaxf(mcur[r], sf[tt][sub][r]);
                }
#pragma unroll
                for (int r = 0; r < 4; ++r) {
                    mcur[r] = fmaxf(mcur[r], __shfl_xor(mcur[r], 1));
                    mcur[r] = fmaxf(mcur[r], __shfl_xor(mcur[r], 2));
                    mcur[r] = fmaxf(mcur[r], __shfl_xor(mcur[r], 4));
                    mcur[r] = fmaxf(mcur[r], __shfl_xor(mcur[r], 8));
                }
                float alpha[4], rs[4];
#pragma unroll
                for (int r = 0; r < 4; ++r) {
                    float mnew = fmaxf(mrow[tt][r], mcur[r]);
                    alpha[r] = EXP2(mrow[tt][r] - mnew);
                    mrow[tt][r] = mnew;
                    rs[r] = 0.f;
                }
#pragma unroll
                for (int sub = 0; sub < 4; ++sub)
#pragma unroll
                    for (int r = 0; r < 4; ++r) {
                        float p = EXP2(sf[tt][sub][r] - mrow[tt][r]);
                        sf[tt][sub][r] = p;
                        rs[r] += p;
                    }
#pragma unroll
                for (int r = 0; r < 4; ++r) {
                    rs[r] += __shfl_xor(rs[r], 1);
                    rs[r] += __shfl_xor(rs[r], 2);
                    rs[r] += __shfl_xor(rs[r], 4);
                    rs[r] += __shfl_xor(rs[r], 8);
                    lrow[tt][r] = lrow[tt][r] * alpha[r] + rs[r];
                }
#pragma unroll
                for (int sd = 0; sd < 4; ++sd)
#pragma unroll
                    for (int r = 0; r < 4; ++r) o[tt][sd][r] *= alpha[r];

                // P (16n x 64s) -> per-wave LDS, bf16, swizzled
#pragma unroll
                for (int sub = 0; sub < 4; ++sub)
#pragma unroll
                    for (int r = 0; r < 4; ++r) {
                        int rr = lg * 4 + r;
                        int col = sub * 16 + l15;
                        *(u16*)(pbase + ((rr * 128 + col * 2) ^ ((rr & 7) << 4))) =
                            f2bf(sf[tt][sub][r]);
                    }
                int pswz = (l15 & 7) << 4;
                bf16x8 pa0 = *(const bf16x8*)(pbase + ((l15 * 128 + lg * 16) ^ pswz));
                bf16x8 pa1 = *(const bf16x8*)(pbase + ((l15 * 128 + lg * 16 + 64) ^ pswz));
#pragma unroll
                for (int sd = 0; sd < 4; ++sd) {
                    int dr = sd * 16 + l15;
                    int vswz = (dr & 7) << 4;
                    bf16x8 v0 = *(const bf16x8*)((char*)sV + ((dr * 128 + lg * 16) ^ vswz));
                    bf16x8 v1 = *(const bf16x8*)((char*)sV + ((dr * 128 + lg * 16 + 64) ^ vswz));
                    o[tt][sd] = __builtin_amdgcn_mfma_f32_16x16x32_bf16(pa0, v0, o[tt][sd], 0, 0, 0);
                    o[tt][sd] = __builtin_amdgcn_mfma_f32_16x16x32_bf16(pa1, v1, o[tt][sd], 0, 0, 0);
                }
            }
            __syncthreads();
        }

#pragma unroll
        for (int tt = 0; tt < 2; ++tt) {
            float inv[4];
#pragma unroll
            for (int r = 0; r < 4; ++r) inv[r] = 1.f / lrow[tt][r];
#pragma unroll
            for (int sd = 0; sd < 4; ++sd)
#pragma unroll
                for (int r = 0; r < 4; ++r) {
                    int n = n0 + w * 32 + tt * 16 + lg * 4 + r;
                    AOb[(size_t)(b * NN + n) * EE + hm * DD + sd * 16 + l15] =
                        f2bf(o[tt][sd][r] * inv[r]);
                }
            if (l15 == 0) {
#pragma unroll
                for (int r = 0; r < 4; ++r) {
                    int n = n0 + w * 32 + tt * 16 + lg * 4 + r;
                    mbuf[(size_t)bh * NN + n] = mrow[tt][r];
                    lbuf[(size_t)bh * NN + n] = inv[r];
                }
            }
        }
    }
}

// ---------------------------------------------------------------------------
// Column sums of probs via MFMA (A = K rows, B = Q^T), balanced pairing.
// ---------------------------------------------------------------------------
__global__ __launch_bounds__(256)
void colsum_mfma(const u16* __restrict__ QKV,
                 const float* __restrict__ mbuf, const float* __restrict__ lbuf,
                 float* __restrict__ AW) {
    int blk = blockIdx.x;
    int pk = blk & 7;
    int bh = blk >> 3;
    int hq = bh & 15;
    int b = bh >> 4;
    int ih = hq >> 2, jh = hq & 3;
    int hm = jh * 4 + ih;
    int t = threadIdx.x;
    int lane = t & 63, w = t >> 6;
    int l15 = lane & 15, lg = lane >> 4;

    for (int half = 0; half < 2; ++half) {
        int stile = half ? (15 - pk) : pk;
        int sb = stile * 128 + w * 32;

        bf16x8 kf[2][2];
#pragma unroll
        for (int st = 0; st < 2; ++st)
#pragma unroll
            for (int h = 0; h < 2; ++h)
                kf[st][h] = *(const bf16x8*)(QKV +
                    (size_t)(b * NN + sb + st * 16 + l15) * QKVW + EE + ih * DD + lg * 8 + h * 32);

        float acc[2][4] = {};
        int nstart = stile * 128;

        const u16* qp0 = QKV + (size_t)(b * NN + nstart + l15) * QKVW + hq * DD + lg * 8;
        bf16x8 q0 = *(const bf16x8*)qp0;
        bf16x8 q1 = *(const bf16x8*)(qp0 + 32);
        float mv = mbuf[(size_t)bh * NN + nstart + l15];
        float li = lbuf[(size_t)bh * NN + nstart + l15];

        for (int nn0 = nstart; nn0 < NN; nn0 += 16) {
            bf16x8 cq0 = q0, cq1 = q1;
            float cmv = mv, cli = li;
            if (nn0 + 16 < NN) {
                const u16* qp = QKV + (size_t)(b * NN + nn0 + 16 + l15) * QKVW + hq * DD + lg * 8;
                q0 = *(const bf16x8*)qp;
                q1 = *(const bf16x8*)(qp + 32);
                mv = mbuf[(size_t)bh * NN + nn0 + 16 + l15];
                li = lbuf[(size_t)bh * NN + nn0 + 16 + l15];
            }
            int n = nn0 + l15;
#pragma unroll
            for (int st = 0; st < 2; ++st) {
                f32x4 z = {0.f, 0.f, 0.f, 0.f};
                z = __builtin_amdgcn_mfma_f32_16x16x32_bf16(kf[st][0], cq0, z, 0, 0, 0);
                z = __builtin_amdgcn_mfma_f32_16x16x32_bf16(kf[st][1], cq1, z, 0, 0, 0);
#pragma unroll
                for (int r = 0; r < 4; ++r) {
                    int s = sb + st * 16 + lg * 4 + r;
                    float val = EXP2(z[r] - cmv) * cli;
                    acc[st][r] += (n >= s) ? val : 0.f;
                }
            }
        }
#pragma unroll
        for (int st = 0; st < 2; ++st)
#pragma unroll
            for (int r = 0; r < 4; ++r) {
                float a = acc[st][r];
                a += __shfl_xor(a, 1);
                a += __shfl_xor(a, 2);
                a += __shfl_xor(a, 4);
                a += __shfl_xor(a, 8);
                if (l15 == 0) {
                    int s = sb + st * 16 + lg * 4 + r;
                    AW[((size_t)b * NN + s) * HQH + hm] = a * (1.0f / NN);
                }
            }
    }
}

// ---------------------------------------------------------------------------
// LayerNorm in place over bf16 rows of length E=1024.
// ---------------------------------------------------------------------------
__global__ __launch_bounds__(256)
void layernorm_bf16(u16* __restrict__ X, const float* __restrict__ g,
                    const float* __restrict__ bt) {
    __shared__ float red[256];
    int row = blockIdx.x;
    int t = threadIdx.x;
    u16* xp = X + (size_t)row * EE;
    ushort4 v = *(ushort4*)&xp[t * 4];
    float x0 = bf2f(v.x), x1 = bf2f(v.y), x2 = bf2f(v.z), x3 = bf2f(v.w);
    red[t] = x0 + x1 + x2 + x3;
    __syncthreads();
    for (int off = 128; off > 0; off >>= 1) {
        if (t < off) red[t] += red[t + off];
        __syncthreads();
    }
    float mu = red[0] * (1.f / EE);
    __syncthreads();
    float d0 = x0 - mu, d1 = x1 - mu, d2 = x2 - mu, d3 = x3 - mu;
    red[t] = d0 * d0 + d1 * d1 + d2 * d2 + d3 * d3;
    __syncthreads();
    for (int off = 128; off > 0; off >>= 1) {
        if (t < off) red[t] += red[t + off];
        __syncthreads();
    }
    float rstd = rsqrtf(red[0] * (1.f / EE) + 1e-5f);
    float4 gg = *(const float4*)&g[t * 4];
    float4 bb = *(const float4*)&bt[t * 4];
    ushort4 o;
    o.x = f2bf(d0 * rstd * gg.x + bb.x);
    o.y = f2bf(d1 * rstd * gg.y + bb.y);
    o.z = f2bf(d2 * rstd * gg.z + bb.z);
    o.w = f2bf(d3 * rstd * gg.w + bb.w);
    *(ushort4*)&xp[t * 4] = o;
}

// ---------------------------------------------------------------------------
extern "C" void kernel_launch(void* const* d_in, const int* in_sizes, int n_in,
                              void* d_out, int out_size, void* d_ws, size_t ws_size,
                              hipStream_t stream) {
    const float* x    = (const float*)d_in[0];
    const float* Wq   = (const float*)d_in[1];
    const float* Wk   = (const float*)d_in[2];
    const float* Wv   = (const float*)d_in[3];
    const float* Wout = (const float*)d_in[4];
    const float* lng  = (const float*)d_in[5];
    const float* lnb  = (const float*)d_in[6];

    float* out = (float*)d_out;                      // [B][N][E]
    float* aw  = out + (size_t)BB * NN * EE;         // [B][N][HQ]

    u16* Xb    = (u16*)d_ws;                         // [4096][1024]
    u16* QKVb  = Xb + (size_t)BB * NN * EE;          // [4096][1536]
    u16* WqkvT = QKVb + (size_t)BB * NN * QKVW;      // [1536][1024]
    u16* WoutT = WqkvT + (size_t)QKVW * EE;          // [1024][1024]
    u16* AOb   = WoutT + (size_t)EE * EE;            // [4096][1024]
    float* mb  = (float*)(AOb + (size_t)BB * NN * EE);
    float* lb  = mb + (size_t)BB * HQH * NN;

    dim3 blk(256);

    conv_bf16<<<BB * NN * EE / 2048, blk, 0, stream>>>(x, Xb);
    transp_bf16<<<dim3(32, 32), blk, 0, stream>>>(Wq, WqkvT, EE);
    transp_bf16<<<dim3(32, 8), blk, 0, stream>>>(Wk, WqkvT + (size_t)EE * EE, KVE);
    transp_bf16<<<dim3(32, 8), blk, 0, stream>>>(Wv, WqkvT + (size_t)(EE + KVE) * EE, KVE);
    transp_bf16<<<dim3(32, 32), blk, 0, stream>>>(Wout, WoutT, EE);

    // Q columns (cols < 1024) pre-scaled by 0.125*log2(e) for exp2 softmax
    gemm_mfma<<<dim3(QKVW / 128, BB * NN / 128), blk, 0, stream>>>(
        Xb, WqkvT, QKVb, EE, QKVW, 1, QSCALE, EE);

    int pblocks = BB * HQH * 8;  // 256, paired q-tiles
    flash_attn<<<pblocks, blk, 0, stream>>>(QKVb, AOb, mb, lb);
    colsum_mfma<<<pblocks, blk, 0, stream>>>(QKVb, mb, lb, aw);

    layernorm_bf16<<<BB * NN, blk, 0, stream>>>(AOb, lng, lnb);

    gemm_mfma<<<dim3(EE / 128, BB * NN / 128), blk, 0, stream>>>(
        AOb, WoutT, out, EE, EE, 0, 1.0f, 0);
}

// Round 7
// 298.033 us; speedup vs baseline: 9.3172x; 1.0597x over previous
//
#include <hip/hip_runtime.h>

#define BB 2
#define NN 2048
#define EE 1024
#define HQH 16
#define DD 64
#define KVE 256
#define QKVW 1536

typedef short bf16x8 __attribute__((ext_vector_type(8)));
typedef short bf16x4 __attribute__((ext_vector_type(4)));
typedef float f32x4 __attribute__((ext_vector_type(4)));
typedef unsigned short u16;
typedef unsigned int u32;

#if __has_builtin(__builtin_amdgcn_exp2f)
#define EXP2(x) __builtin_amdgcn_exp2f(x)
#else
#define EXP2(x) exp2f(x)
#endif

// softmax scale 1/sqrt(64) folded with log2(e) so we can use raw exp2
#define QSCALE 0.18033688011112042f

__device__ __forceinline__ u16 f2bf(float f) {
    unsigned u = __float_as_uint(f);
    u += 0x7FFFu + ((u >> 16) & 1u);
    return (u16)(u >> 16);
}
__device__ __forceinline__ float bf2f(u16 h) {
    return __uint_as_float(((unsigned)h) << 16);
}
// packed RNE f32x2 -> bf16x2 (dst.lo = a, dst.hi = b)
__device__ __forceinline__ u32 cvtpk(float a, float b) {
    u32 r;
    asm("v_cvt_pk_bf16_f32 %0, %1, %2" : "=v"(r) : "v"(a), "v"(b));
    return r;
}

#define GLOAD_LDS16(gp, lp) __builtin_amdgcn_global_load_lds( \
    (const __attribute__((address_space(1))) unsigned int*)(gp), \
    (__attribute__((address_space(3))) unsigned int*)(lp), 16, 0, 0)

// 8x8 bf16 transpose across 8 consecutive lanes (q = lane&7).
__device__ __forceinline__ bf16x8 xpose8(bf16x8 v, int q) {
    union { bf16x8 v; u32 r[4]; } u_;
    u_.v = v;
    u32 r0 = u_.r[0], r1 = u_.r[1], r2 = u_.r[2], r3 = u_.r[3];
    u32 x, y, t0;
    x = (q & 4) ? r0 : r2;  y = (q & 4) ? r1 : r3;
    x = __shfl_xor(x, 4);   y = __shfl_xor(y, 4);
    if (q & 4) { r0 = x; r1 = y; } else { r2 = x; r3 = y; }
    x = (q & 2) ? r0 : r1;  y = (q & 2) ? r2 : r3;
    x = __shfl_xor(x, 2);   y = __shfl_xor(y, 2);
    if (q & 2) { r0 = x; r2 = y; } else { r1 = x; r3 = y; }
    t0 = __shfl_xor(r0, 1); r0 = (q & 1) ? ((t0 >> 16) | (r0 & 0xFFFF0000u)) : ((r0 & 0xFFFFu) | (t0 << 16));
    t0 = __shfl_xor(r1, 1); r1 = (q & 1) ? ((t0 >> 16) | (r1 & 0xFFFF0000u)) : ((r1 & 0xFFFFu) | (t0 << 16));
    t0 = __shfl_xor(r2, 1); r2 = (q & 1) ? ((t0 >> 16) | (r2 & 0xFFFF0000u)) : ((r2 & 0xFFFFu) | (t0 << 16));
    t0 = __shfl_xor(r3, 1); r3 = (q & 1) ? ((t0 >> 16) | (r3 & 0xFFFF0000u)) : ((r3 & 0xFFFFu) | (t0 << 16));
    u_.r[0] = r0; u_.r[1] = r1; u_.r[2] = r2; u_.r[3] = r3;
    return u_.v;
}

// ---------------------------------------------------------------------------
__global__ __launch_bounds__(256)
void conv_bf16(const float* __restrict__ in, u16* __restrict__ out) {
    int i = (blockIdx.x * 256 + threadIdx.x) * 8;
    float4 a = *(const float4*)&in[i];
    float4 b = *(const float4*)&in[i + 4];
    bf16x8 p;
    p[0] = f2bf(a.x); p[1] = f2bf(a.y); p[2] = f2bf(a.z); p[3] = f2bf(a.w);
    p[4] = f2bf(b.x); p[5] = f2bf(b.y); p[6] = f2bf(b.z); p[7] = f2bf(b.w);
    *(bf16x8*)&out[i] = p;
}

// ---------------------------------------------------------------------------
__global__ __launch_bounds__(256)
void transp_bf16(const float* __restrict__ W, u16* __restrict__ WT, int Nc) {
    __shared__ float tile[32][33];
    int k0 = blockIdx.x * 32, n0 = blockIdx.y * 32;
    int tx = threadIdx.x & 31, ty = threadIdx.x >> 5;
#pragma unroll
    for (int i = 0; i < 4; ++i)
        tile[ty + i * 8][tx] = W[(size_t)(k0 + ty + i * 8) * Nc + n0 + tx];
    __syncthreads();
#pragma unroll
    for (int i = 0; i < 4; ++i)
        WT[(size_t)(n0 + ty + i * 8) * EE + k0 + tx] = f2bf(tile[tx][ty + i * 8]);
}

// ---------------------------------------------------------------------------
// MFMA bf16 GEMM (m97 structure). Epilogue scales cols < nq by qscale.
// ---------------------------------------------------------------------------
__global__ __launch_bounds__(256)
void gemm_mfma(const u16* __restrict__ A, const u16* __restrict__ BT,
               void* __restrict__ C, int K, int ldc, int obf16,
               float qscale, int nq) {
    __shared__ __attribute__((aligned(16))) u16 sA[128 * 64];
    __shared__ __attribute__((aligned(16))) u16 sB[128 * 64];
    int t = threadIdx.x;
    int lane = t & 63, w = t >> 6;
    int wr = w >> 1, wc = w & 1;
    int l15 = lane & 15, lg = lane >> 4;
    int m0 = blockIdx.y * 128, n0 = blockIdx.x * 128;

    f32x4 acc[4][4];
#pragma unroll
    for (int mi = 0; mi < 4; ++mi)
#pragma unroll
        for (int ni = 0; ni < 4; ++ni) acc[mi][ni] = (f32x4){0.f, 0.f, 0.f, 0.f};

    int srow = lane >> 3;
    int schunk = (lane & 7) ^ srow;
    const u16* ga = A + (size_t)(m0 + w * 32 + srow) * K + schunk * 8;
    const u16* gb = BT + (size_t)(n0 + w * 32 + srow) * K + schunk * 8;
    char* lA = (char*)sA + w * 4096;
    char* lB = (char*)sB + w * 4096;

    for (int k0 = 0; k0 < K; k0 += 64) {
#pragma unroll
        for (int i = 0; i < 4; ++i) {
            GLOAD_LDS16(ga + (size_t)i * 8 * K + k0, lA + i * 1024);
            GLOAD_LDS16(gb + (size_t)i * 8 * K + k0, lB + i * 1024);
        }
        __syncthreads();
#pragma unroll
        for (int ks = 0; ks < 2; ++ks) {
            bf16x8 af[4], bfr[4];
#pragma unroll
            for (int mi = 0; mi < 4; ++mi) {
                int row = wr * 64 + mi * 16 + l15;
                af[mi] = *(const bf16x8*)((char*)sA +
                    ((row * 128 + lg * 16 + ks * 64) ^ ((row & 7) << 4)));
            }
#pragma unroll
            for (int ni = 0; ni < 4; ++ni) {
                int row = wc * 64 + ni * 16 + l15;
                bfr[ni] = *(const bf16x8*)((char*)sB +
                    ((row * 128 + lg * 16 + ks * 64) ^ ((row & 7) << 4)));
            }
#pragma unroll
            for (int mi = 0; mi < 4; ++mi)
#pragma unroll
                for (int ni = 0; ni < 4; ++ni)
                    acc[mi][ni] = __builtin_amdgcn_mfma_f32_16x16x32_bf16(
                        af[mi], bfr[ni], acc[mi][ni], 0, 0, 0);
        }
        __syncthreads();
    }

#pragma unroll
    for (int mi = 0; mi < 4; ++mi) {
        int rbase = m0 + wr * 64 + mi * 16 + lg * 4;
#pragma unroll
        for (int ni = 0; ni < 4; ++ni) {
            int col = n0 + wc * 64 + ni * 16 + l15;
            float sc = (col < nq) ? qscale : 1.0f;
            if (obf16) {
                u16* Cb = (u16*)C;
#pragma unroll
                for (int r = 0; r < 4; ++r)
                    Cb[(size_t)(rbase + r) * ldc + col] = f2bf(acc[mi][ni][r] * sc);
            } else {
                float* Cf = (float*)C;
#pragma unroll
                for (int r = 0; r < 4; ++r)
                    Cf[(size_t)(rbase + r) * ldc + col] = acc[mi][ni][r] * sc;
            }
        }
    }
}

// ---------------------------------------------------------------------------
// Flash attention v3: swapped QK^T (S = mfma(K, Q)) so each lane owns P for
// q-row l15 -> P stays in registers (cvt_pk into PV A-frags with permuted k;
// V LDS b64 reads supply the matching k-order). K direct from global (L2),
// V double-buffered in LDS (1 barrier/tile). Defer-max rescale (THR=8).
// Grid 512 = (b, hq, ntile), heavy tiles first, dynamic balance.
// ---------------------------------------------------------------------------
__global__ __launch_bounds__(256)
void flash_attn(const u16* __restrict__ QKV, u16* __restrict__ AOb,
                float* __restrict__ mbuf, float* __restrict__ lbuf) {
    __shared__ __attribute__((aligned(16))) u16 sV[2][64 * 64];  // [d][s] swz

    int blk = blockIdx.x;
    int ntile = 15 - (blk & 15);     // heavy first
    int bh = blk >> 4;
    int hq = bh & 15;
    int b = bh >> 4;
    int ih = hq >> 2, jh = hq & 3;
    int hm = jh * 4 + ih;
    int n0 = ntile * 128;
    int t = threadIdx.x;
    int lane = t & 63, w = t >> 6;
    int l15 = lane & 15, lg = lane >> 4;
    int q8 = t & 7;

    const u16* Kg = QKV + (size_t)b * NN * QKVW + EE + ih * DD;
    const u16* Vg = QKV + (size_t)b * NN * QKVW + EE + KVE + jh * DD;

    // Q B-frags: B[k=d][n=qrow]: lane holds Q[row l15][d = lg*8+i (+32h)]
    bf16x8 qf[2][2];
#pragma unroll
    for (int tt = 0; tt < 2; ++tt)
#pragma unroll
        for (int h = 0; h < 2; ++h)
            qf[tt][h] = *(const bf16x8*)(QKV +
                (size_t)(b * NN + n0 + w * 32 + tt * 16 + l15) * QKVW + hq * DD + lg * 8 + h * 32);

    f32x4 o[2][4];
    float mrow[2] = {-1e30f, -1e30f};   // per q-row (row = l15, dup over lg)
    float lrow[2] = {0.f, 0.f};
#pragma unroll
    for (int tt = 0; tt < 2; ++tt)
#pragma unroll
        for (int i = 0; i < 4; ++i) o[tt][i] = (f32x4){0.f, 0.f, 0.f, 0.f};

    int nt = (n0 + 128) >> 6;   // 64-wide KV tiles
    // V load pattern: lin = t + it*256; s = (lin>>6)*8 + q8, dchunk = ((lin>>3)&7)*8
    bf16x8 vr[2];
#pragma unroll
    for (int it = 0; it < 2; ++it) {
        int lin = t + it * 256;
        vr[it] = *(const bf16x8*)(Vg + (size_t)((lin >> 6) * 8 + q8) * QKVW + ((lin >> 3) & 7) * 8);
    }
    // write tile 0 into buf 0
#pragma unroll
    for (int it = 0; it < 2; ++it) {
        int lin = t + it * 256;
        int d = ((lin >> 3) & 7) * 8 + q8;
        int sbase = (lin >> 6) * 8;
        bf16x8 vt = xpose8(vr[it], q8);
        *(bf16x8*)((char*)sV[0] + ((d * 128 + sbase * 2) ^ (q8 << 4))) = vt;
    }

    for (int ti = 0; ti < nt; ++ti) {
        int s0 = ti << 6;
        // issue next V tile global loads (latency hides under compute)
        if (ti + 1 < nt) {
#pragma unroll
            for (int it = 0; it < 2; ++it) {
                int lin = t + it * 256;
                vr[it] = *(const bf16x8*)(Vg +
                    (size_t)(s0 + 64 + (lin >> 6) * 8 + q8) * QKVW + ((lin >> 3) & 7) * 8);
            }
        }
        __syncthreads();   // buf[ti&1] writes visible; prior reads of buf[ti&1] done
        const char* vb = (const char*)sV[ti & 1];

        // K A-frags direct from global: A[m=s][k=d]: lane holds K[s0+sub*16+l15][lg*8+i+32h]
        // S = K·Q^T per sub, both tt
        f32x4 sf[2][4];
#pragma unroll
        for (int sub = 0; sub < 4; ++sub) {
            const u16* kp = Kg + (size_t)(s0 + sub * 16 + l15) * QKVW + lg * 8;
            bf16x8 k0 = *(const bf16x8*)kp;
            bf16x8 k1 = *(const bf16x8*)(kp + 32);
#pragma unroll
            for (int tt = 0; tt < 2; ++tt) {
                f32x4 z = {0.f, 0.f, 0.f, 0.f};
                z = __builtin_amdgcn_mfma_f32_16x16x32_bf16(k0, qf[tt][0], z, 0, 0, 0);
                sf[tt][sub] = __builtin_amdgcn_mfma_f32_16x16x32_bf16(k1, qf[tt][1], z, 0, 0, 0);
            }
        }

        // V B-frags from LDS (permuted k-order): per sd, frag f: s = f*32 + {lg*4+j, 16+lg*4+j}
        bf16x8 vf[4][2];
#pragma unroll
        for (int sd = 0; sd < 4; ++sd) {
            int d = sd * 16 + l15;
            int swz = (d & 7) << 4;
#pragma unroll
            for (int f = 0; f < 2; ++f) {
                int aA = (d * 128 + (f * 32 + lg * 4) * 2) ^ swz;
                int aB = (d * 128 + (f * 32 + 16 + lg * 4) * 2) ^ swz;
                bf16x4 lo = *(const bf16x4*)(vb + aA);
                bf16x4 hi = *(const bf16x4*)(vb + aB);
                bf16x8 vv;
                vv[0] = lo[0]; vv[1] = lo[1]; vv[2] = lo[2]; vv[3] = lo[3];
                vv[4] = hi[0]; vv[5] = hi[1]; vv[6] = hi[2]; vv[7] = hi[3];
                vf[sd][f] = vv;
            }
        }

#pragma unroll
        for (int tt = 0; tt < 2; ++tt) {
            int ng_min = n0 + w * 32 + tt * 16;
            int ng = ng_min + l15;
            float mcur = -1e30f;
            if (s0 + 63 > ng_min) {   // diagonal (or fully-masked) tile
#pragma unroll
                for (int sub = 0; sub < 4; ++sub)
#pragma unroll
                    for (int r = 0; r < 4; ++r) {
                        int sg = s0 + sub * 16 + lg * 4 + r;
                        float sc = (sg <= ng) ? sf[tt][sub][r] : -1e30f;
                        sf[tt][sub][r] = sc;
                        mcur = fmaxf(mcur, sc);
                    }
            } else {
#pragma unroll
                for (int sub = 0; sub < 4; ++sub)
#pragma unroll
                    for (int r = 0; r < 4; ++r) mcur = fmaxf(mcur, sf[tt][sub][r]);
            }
            mcur = fmaxf(mcur, __shfl_xor(mcur, 16));
            mcur = fmaxf(mcur, __shfl_xor(mcur, 32));

            float mn = mrow[tt];
            if (!__all(mcur <= mn + 8.0f)) {      // T13 defer-max
                mn = fmaxf(mn, mcur);
                float alpha = EXP2(mrow[tt] - mn);
                mrow[tt] = mn;
                lrow[tt] *= alpha;
                float a0 = __shfl(alpha, lg * 4 + 0);
                float a1 = __shfl(alpha, lg * 4 + 1);
                float a2 = __shfl(alpha, lg * 4 + 2);
                float a3 = __shfl(alpha, lg * 4 + 3);
#pragma unroll
                for (int sd = 0; sd < 4; ++sd) {
                    o[tt][sd][0] *= a0; o[tt][sd][1] *= a1;
                    o[tt][sd][2] *= a2; o[tt][sd][3] *= a3;
                }
            }
            float rs = 0.f;
#pragma unroll
            for (int sub = 0; sub < 4; ++sub)
#pragma unroll
                for (int r = 0; r < 4; ++r) {
                    float p = EXP2(sf[tt][sub][r] - mn);
                    sf[tt][sub][r] = p;
                    rs += p;
                }
            rs += __shfl_xor(rs, 16);
            rs += __shfl_xor(rs, 32);
            lrow[tt] += rs;

            // pack P into PV A-frags (k-permuted: i<4 -> s=lg*4+i; i>=4 -> s=16+lg*4+i)
            union { u32 r[4]; bf16x8 v; } pa0, pa1;
            pa0.r[0] = cvtpk(sf[tt][0][0], sf[tt][0][1]);
            pa0.r[1] = cvtpk(sf[tt][0][2], sf[tt][0][3]);
            pa0.r[2] = cvtpk(sf[tt][1][0], sf[tt][1][1]);
            pa0.r[3] = cvtpk(sf[tt][1][2], sf[tt][1][3]);
            pa1.r[0] = cvtpk(sf[tt][2][0], sf[tt][2][1]);
            pa1.r[1] = cvtpk(sf[tt][2][2], sf[tt][2][3]);
            pa1.r[2] = cvtpk(sf[tt][3][0], sf[tt][3][1]);
            pa1.r[3] = cvtpk(sf[tt][3][2], sf[tt][3][3]);
#pragma unroll
            for (int sd = 0; sd < 4; ++sd) {
                o[tt][sd] = __builtin_amdgcn_mfma_f32_16x16x32_bf16(pa0.v, vf[sd][0], o[tt][sd], 0, 0, 0);
                o[tt][sd] = __builtin_amdgcn_mfma_f32_16x16x32_bf16(pa1.v, vf[sd][1], o[tt][sd], 0, 0, 0);
            }
        }

        // write next V tile into the other buffer (readers of buf[ti&1] may lag;
        // different buffer, so safe; next iter's barrier orders write->read)
        if (ti + 1 < nt) {
#pragma unroll
            for (int it = 0; it < 2; ++it) {
                int lin = t + it * 256;
                int d = ((lin >> 3) & 7) * 8 + q8;
                int sbase = (lin >> 6) * 8;
                bf16x8 vt = xpose8(vr[it], q8);
                *(bf16x8*)((char*)sV[(ti + 1) & 1] + ((d * 128 + sbase * 2) ^ (q8 << 4))) = vt;
            }
        }
    }

#pragma unroll
    for (int tt = 0; tt < 2; ++tt) {
        float linv = 1.f / lrow[tt];       // for q-row l15
        if (lg == 0) {
            int n = n0 + w * 32 + tt * 16 + l15;
            mbuf[(size_t)bh * NN + n] = mrow[tt];
            lbuf[(size_t)bh * NN + n] = linv;
        }
        float i0 = __shfl(linv, lg * 4 + 0);
        float i1 = __shfl(linv, lg * 4 + 1);
        float i2 = __shfl(linv, lg * 4 + 2);
        float i3 = __shfl(linv, lg * 4 + 3);
#pragma unroll
        for (int sd = 0; sd < 4; ++sd) {
            int nb = n0 + w * 32 + tt * 16 + lg * 4;
            size_t base = (size_t)(b * NN + nb) * EE + hm * DD + sd * 16 + l15;
            AOb[base]          = f2bf(o[tt][sd][0] * i0);
            AOb[base + EE]     = f2bf(o[tt][sd][1] * i1);
            AOb[base + 2 * EE] = f2bf(o[tt][sd][2] * i2);
            AOb[base + 3 * EE] = f2bf(o[tt][sd][3] * i3);
        }
    }
}

// ---------------------------------------------------------------------------
// Column sums of probs via MFMA (A = K rows, B = Q^T). Grid 512, dynamic.
// ---------------------------------------------------------------------------
__global__ __launch_bounds__(256)
void colsum_mfma(const u16* __restrict__ QKV,
                 const float* __restrict__ mbuf, const float* __restrict__ lbuf,
                 float* __restrict__ AW) {
    int blk = blockIdx.x;
    int stile = blk & 15;
    int bh = blk >> 4;
    int hq = bh & 15;
    int b = bh >> 4;
    int ih = hq >> 2, jh = hq & 3;
    int hm = jh * 4 + ih;
    int t = threadIdx.x;
    int lane = t & 63, w = t >> 6;
    int l15 = lane & 15, lg = lane >> 4;
    int sb = stile * 128 + w * 32;

    bf16x8 kf[2][2];
#pragma unroll
    for (int st = 0; st < 2; ++st)
#pragma unroll
        for (int h = 0; h < 2; ++h)
            kf[st][h] = *(const bf16x8*)(QKV +
                (size_t)(b * NN + sb + st * 16 + l15) * QKVW + EE + ih * DD + lg * 8 + h * 32);

    float acc[2][4] = {};
    int nstart = stile * 128;

    const u16* qp0 = QKV + (size_t)(b * NN + nstart + l15) * QKVW + hq * DD + lg * 8;
    bf16x8 q0 = *(const bf16x8*)qp0;
    bf16x8 q1 = *(const bf16x8*)(qp0 + 32);
    float mv = mbuf[(size_t)bh * NN + nstart + l15];
    float li = lbuf[(size_t)bh * NN + nstart + l15];

    for (int nn0 = nstart; nn0 < NN; nn0 += 16) {
        bf16x8 cq0 = q0, cq1 = q1;
        float cmv = mv, cli = li;
        if (nn0 + 16 < NN) {
            const u16* qp = QKV + (size_t)(b * NN + nn0 + 16 + l15) * QKVW + hq * DD + lg * 8;
            q0 = *(const bf16x8*)qp;
            q1 = *(const bf16x8*)(qp + 32);
            mv = mbuf[(size_t)bh * NN + nn0 + 16 + l15];
            li = lbuf[(size_t)bh * NN + nn0 + 16 + l15];
        }
        int n = nn0 + l15;
#pragma unroll
        for (int st = 0; st < 2; ++st) {
            f32x4 z = {0.f, 0.f, 0.f, 0.f};
            z = __builtin_amdgcn_mfma_f32_16x16x32_bf16(kf[st][0], cq0, z, 0, 0, 0);
            z = __builtin_amdgcn_mfma_f32_16x16x32_bf16(kf[st][1], cq1, z, 0, 0, 0);
#pragma unroll
            for (int r = 0; r < 4; ++r) {
                int s = sb + st * 16 + lg * 4 + r;
                float val = EXP2(z[r] - cmv) * cli;
                acc[st][r] += (n >= s) ? val : 0.f;
            }
        }
    }
#pragma unroll
    for (int st = 0; st < 2; ++st)
#pragma unroll
        for (int r = 0; r < 4; ++r) {
            float a = acc[st][r];
            a += __shfl_xor(a, 1);
            a += __shfl_xor(a, 2);
            a += __shfl_xor(a, 4);
            a += __shfl_xor(a, 8);
            if (l15 == 0) {
                int s = sb + st * 16 + lg * 4 + r;
                AW[((size_t)b * NN + s) * HQH + hm] = a * (1.0f / NN);
            }
        }
}

// ---------------------------------------------------------------------------
__global__ __launch_bounds__(256)
void layernorm_bf16(u16* __restrict__ X, const float* __restrict__ g,
                    const float* __restrict__ bt) {
    __shared__ float red[256];
    int row = blockIdx.x;
    int t = threadIdx.x;
    u16* xp = X + (size_t)row * EE;
    ushort4 v = *(ushort4*)&xp[t * 4];
    float x0 = bf2f(v.x), x1 = bf2f(v.y), x2 = bf2f(v.z), x3 = bf2f(v.w);
    red[t] = x0 + x1 + x2 + x3;
    __syncthreads();
    for (int off = 128; off > 0; off >>= 1) {
        if (t < off) red[t] += red[t + off];
        __syncthreads();
    }
    float mu = red[0] * (1.f / EE);
    __syncthreads();
    float d0 = x0 - mu, d1 = x1 - mu, d2 = x2 - mu, d3 = x3 - mu;
    red[t] = d0 * d0 + d1 * d1 + d2 * d2 + d3 * d3;
    __syncthreads();
    for (int off = 128; off > 0; off >>= 1) {
        if (t < off) red[t] += red[t + off];
        __syncthreads();
    }
    float rstd = rsqrtf(red[0] * (1.f / EE) + 1e-5f);
    float4 gg = *(const float4*)&g[t * 4];
    float4 bb = *(const float4*)&bt[t * 4];
    ushort4 o;
    o.x = f2bf(d0 * rstd * gg.x + bb.x);
    o.y = f2bf(d1 * rstd * gg.y + bb.y);
    o.z = f2bf(d2 * rstd * gg.z + bb.z);
    o.w = f2bf(d3 * rstd * gg.w + bb.w);
    *(ushort4*)&xp[t * 4] = o;
}

// ---------------------------------------------------------------------------
extern "C" void kernel_launch(void* const* d_in, const int* in_sizes, int n_in,
                              void* d_out, int out_size, void* d_ws, size_t ws_size,
                              hipStream_t stream) {
    const float* x    = (const float*)d_in[0];
    const float* Wq   = (const float*)d_in[1];
    const float* Wk   = (const float*)d_in[2];
    const float* Wv   = (const float*)d_in[3];
    const float* Wout = (const float*)d_in[4];
    const float* lng  = (const float*)d_in[5];
    const float* lnb  = (const float*)d_in[6];

    float* out = (float*)d_out;                      // [B][N][E]
    float* aw  = out + (size_t)BB * NN * EE;         // [B][N][HQ]

    u16* Xb    = (u16*)d_ws;                         // [4096][1024]
    u16* QKVb  = Xb + (size_t)BB * NN * EE;          // [4096][1536]
    u16* WqkvT = QKVb + (size_t)BB * NN * QKVW;      // [1536][1024]
    u16* WoutT = WqkvT + (size_t)QKVW * EE;          // [1024][1024]
    u16* AOb   = WoutT + (size_t)EE * EE;            // [4096][1024]
    float* mb  = (float*)(AOb + (size_t)BB * NN * EE);
    float* lb  = mb + (size_t)BB * HQH * NN;

    dim3 blk(256);

    conv_bf16<<<BB * NN * EE / 2048, blk, 0, stream>>>(x, Xb);
    transp_bf16<<<dim3(32, 32), blk, 0, stream>>>(Wq, WqkvT, EE);
    transp_bf16<<<dim3(32, 8), blk, 0, stream>>>(Wk, WqkvT + (size_t)EE * EE, KVE);
    transp_bf16<<<dim3(32, 8), blk, 0, stream>>>(Wv, WqkvT + (size_t)(EE + KVE) * EE, KVE);
    transp_bf16<<<dim3(32, 32), blk, 0, stream>>>(Wout, WoutT, EE);

    gemm_mfma<<<dim3(QKVW / 128, BB * NN / 128), blk, 0, stream>>>(
        Xb, WqkvT, QKVb, EE, QKVW, 1, QSCALE, EE);

    int ablocks = BB * HQH * 16;  // 512, unpaired, dynamic balance
    flash_attn<<<ablocks, blk, 0, stream>>>(QKVb, AOb, mb, lb);
    colsum_mfma<<<ablocks, blk, 0, stream>>>(QKVb, mb, lb, aw);

    layernorm_bf16<<<BB * NN, blk, 0, stream>>>(AOb, lng, lnb);

    gemm_mfma<<<dim3(EE / 128, BB * NN / 128), blk, 0, stream>>>(
        AOb, WoutT, out, EE, EE, 0, 1.0f, 0);
}